// Round 1
// baseline (833.949 us; speedup 1.0000x reference)
//
#include <hip/hip_runtime.h>
#include <cstdint>

// ---------------- types ----------------
typedef __bf16 bf16_t;
typedef __bf16 bf16x8 __attribute__((ext_vector_type(8)));
typedef __bf16 bf16x4 __attribute__((ext_vector_type(4)));
typedef float  f32x4  __attribute__((ext_vector_type(4)));
typedef bf16x8 __attribute__((may_alias)) bf16x8a;
typedef bf16x4 __attribute__((may_alias)) bf16x4a;
typedef f32x4  __attribute__((may_alias)) f32x4a;

#define S_LEN 2048
#define HDIM  2048
#define NHEAD 16
#define HD    128
#define TSD   512
#define BROWS 4096   // B * S
#define KIDX  459    // K_IDX - 1

__device__ __forceinline__ f32x4 mfma_bf16(bf16x8 a, bf16x8 b, f32x4 c) {
  return __builtin_amdgcn_mfma_f32_16x16x32_bf16(a, b, c, 0, 0, 0);
}

__device__ __forceinline__ void gld_lds16(const bf16_t* g, bf16_t* l) {
  __builtin_amdgcn_global_load_lds(
      (__attribute__((address_space(1))) void*)(void*)const_cast<bf16_t*>(g),
      (__attribute__((address_space(3))) void*)(void*)(l), 16, 0, 0);
}

// ---------------- elementwise convert fp32 -> bf16 ----------------
__global__ void k_cvt(const float* __restrict__ in, bf16_t* __restrict__ out, int n) {
  int i = (blockIdx.x * 256 + threadIdx.x) * 4;
  if (i >= n) return;
  f32x4 v = *(const f32x4a*)(in + i);
  bf16x4 o = { (bf16_t)v.x, (bf16_t)v.y, (bf16_t)v.z, (bf16_t)v.w };
  *(bf16x4a*)(out + i) = o;
}

// ---------------- transpose + convert: out[c][r] = in[r][c] ----------------
__global__ void k_transpose(const float* __restrict__ in, bf16_t* __restrict__ out,
                            int R, int C, int ldin) {
  __shared__ float tile[32][33];
  int c0 = blockIdx.x * 32, r0 = blockIdx.y * 32;
  int tx = threadIdx.x, ty = threadIdx.y;
  for (int i = ty; i < 32; i += 8)
    tile[i][tx] = in[(size_t)(r0 + i) * ldin + c0 + tx];
  __syncthreads();
  for (int i = ty; i < 32; i += 8)
    out[(size_t)(c0 + i) * R + r0 + tx] = (bf16_t)tile[tx][i];
}

// ---------------- bf16 MFMA GEMM, B pre-transposed (N x K) ----------------
// MODE 0: fp32 store to outF[row*N+col]
// MODE 1: bf16 store to outB[row*N+col]
// MODE 2: acc + addend[row*addLd + addCol + col], bf16 store permuted [b,h,s,d]
template<int MODE>
__global__ __launch_bounds__(256)
void k_gemm(const bf16_t* __restrict__ A, const bf16_t* __restrict__ Bt,
            float* __restrict__ outF, bf16_t* __restrict__ outB,
            const bf16_t* __restrict__ addend, int M, int N, int K,
            int addLd, int addCol)
{
  __shared__ __align__(16) bf16_t As[128 * 32];
  __shared__ __align__(16) bf16_t Bs[128 * 32];
  const int tid  = threadIdx.x;
  const int lane = tid & 63, w = tid >> 6;
  const int quad = lane >> 4, l15 = lane & 15;
  const int m0 = blockIdx.y * 128, n0 = blockIdx.x * 128;
  const int wm = (w >> 1) * 64, wn = (w & 1) * 64;

  f32x4 acc[4][4];
#pragma unroll
  for (int i = 0; i < 4; i++)
#pragma unroll
    for (int j = 0; j < 4; j++) { f32x4 z = {0.f,0.f,0.f,0.f}; acc[i][j] = z; }

  const int srow = w * 16 + (lane >> 2);   // row within 64-row half-tile
  const int scol = (lane & 3) * 8;         // k offset within 32

  for (int k0 = 0; k0 < K; k0 += 32) {
    __syncthreads();
    gld_lds16(A  + (size_t)(m0 +      srow) * K + k0 + scol, As + (size_t)w * 512);
    gld_lds16(A  + (size_t)(m0 + 64 + srow) * K + k0 + scol, As + (size_t)(4 + w) * 512);
    gld_lds16(Bt + (size_t)(n0 +      srow) * K + k0 + scol, Bs + (size_t)w * 512);
    gld_lds16(Bt + (size_t)(n0 + 64 + srow) * K + k0 + scol, Bs + (size_t)(4 + w) * 512);
    __syncthreads();
    bf16x8 af[4], bv[4];
#pragma unroll
    for (int i = 0; i < 4; i++)
      af[i] = *(const bf16x8a*)&As[(wm + i * 16 + l15) * 32 + quad * 8];
#pragma unroll
    for (int j = 0; j < 4; j++)
      bv[j] = *(const bf16x8a*)&Bs[(wn + j * 16 + l15) * 32 + quad * 8];
#pragma unroll
    for (int i = 0; i < 4; i++)
#pragma unroll
      for (int j = 0; j < 4; j++)
        acc[i][j] = mfma_bf16(af[i], bv[j], acc[i][j]);
  }

#pragma unroll
  for (int i = 0; i < 4; i++)
#pragma unroll
    for (int j = 0; j < 4; j++)
#pragma unroll
      for (int r = 0; r < 4; r++) {
        int row = m0 + wm + i * 16 + quad * 4 + r;
        int col = n0 + wn + j * 16 + l15;
        float v = acc[i][j][r];
        if (MODE == 0) {
          outF[(size_t)row * N + col] = v;
        } else if (MODE == 1) {
          outB[(size_t)row * N + col] = (bf16_t)v;
        } else {
          v += (float)addend[(size_t)row * addLd + addCol + col];
          int s = row & (S_LEN - 1), b = row >> 11;
          int h = col >> 7, d = col & (HD - 1);
          outB[(((size_t)(b * NHEAD + h) * S_LEN) + s) * HD + d] = (bf16_t)v;
        }
      }
}

// ---------------- blend + rmsnorm + kth-threshold + relu ----------------
__global__ __launch_bounds__(256)
void k_tsproc(const float* __restrict__ ts, const float* __restrict__ lte,
              const float* __restrict__ wn, bf16_t* __restrict__ tsf)
{
  __shared__ float sv[TSD];
  __shared__ float red[4];
  int row = blockIdx.x;
  int t = threadIdx.x;
  const float* tr = ts  + (size_t)row * TSD;
  const float* lr = lte + (size_t)row * TSD;
  float v0 = 0.5f * tr[t] + 0.5f * lr[t];
  float v1 = 0.5f * tr[t + 256] + 0.5f * lr[t + 256];
  float ss = v0 * v0 + v1 * v1;
#pragma unroll
  for (int o = 32; o > 0; o >>= 1) ss += __shfl_down(ss, o);
  int lane = t & 63, wv = t >> 6;
  if (lane == 0) red[wv] = ss;
  __syncthreads();
  float tot = red[0] + red[1] + red[2] + red[3];
  float scl = rsqrtf(tot * (1.0f / TSD) + 1e-6f);
  float n0 = v0 * scl * wn[t];
  float n1 = v1 * scl * wn[t + 256];
  sv[t] = n0; sv[t + 256] = n1;
  __syncthreads();
  // bitonic sort ascending over 512
  for (int k = 2; k <= TSD; k <<= 1) {
    for (int j = k >> 1; j > 0; j >>= 1) {
#pragma unroll
      for (int u = 0; u < 2; u++) {
        int idx = t + u * 256;
        int ixj = idx ^ j;
        if (ixj > idx) {
          float a = sv[idx], b = sv[ixj];
          bool up = ((idx & k) == 0);
          if ((a > b) == up) { sv[idx] = b; sv[ixj] = a; }
        }
      }
      __syncthreads();
    }
  }
  float kth = sv[KIDX];
  tsf[(size_t)row * TSD + t]       = (bf16_t)fmaxf(n0 - kth, 0.0f);
  tsf[(size_t)row * TSD + t + 256] = (bf16_t)fmaxf(n1 - kth, 0.0f);
}

// ---------------- RoPE in place on [B*NH, S, HD] bf16 ----------------
__global__ void k_rope(bf16_t* __restrict__ x) {
  int gid = blockIdx.x * 256 + threadIdx.x;    // 65536 rows * 64 pairs
  int d = gid & 63;
  int rowi = gid >> 6;
  int s = rowi & (S_LEN - 1);
  bf16_t* p = x + (size_t)rowi * HD;
  float inv = powf(10000.0f, (float)(-2 * d) * (1.0f / 128.0f));
  float ang = (float)s * inv;
  float sn, c;
  sincosf(ang, &sn, &c);
  float x0 = (float)p[d], x1 = (float)p[d + 64];
  p[d]      = (bf16_t)(x0 * c - x1 * sn);
  p[d + 64] = (bf16_t)(x1 * c + x0 * sn);
}

// ---------------- flash attention (causal) ----------------
__global__ __launch_bounds__(256)
void k_attn(const bf16_t* __restrict__ qb, const bf16_t* __restrict__ kb,
            const bf16_t* __restrict__ vb, bf16_t* __restrict__ attnB)
{
  constexpr int KT_STR = 136;  // padded K-tile stride
  constexpr int V_STR  = 72;   // padded V^T stride
  constexpr int P_STR  = 72;   // padded P stride
  __shared__ __align__(16) bf16_t Kt[64 * KT_STR];
  __shared__ __align__(16) bf16_t Vt[HD * V_STR];
  __shared__ __align__(16) bf16_t Pt[64 * P_STR];

  const int bh = blockIdx.y;
  const int q0 = blockIdx.x * 64;
  const int tid = threadIdx.x;
  const int lane = tid & 63, w = tid >> 6;
  const int quad = lane >> 4, l15 = lane & 15;

  const bf16_t* Q  = qb + (size_t)bh * S_LEN * HD;
  const bf16_t* Kg = kb + (size_t)bh * S_LEN * HD;
  const bf16_t* Vg = vb + (size_t)bh * S_LEN * HD;

  bf16x8 qf[4];
  {
    const bf16_t* qrow = Q + (size_t)(q0 + w * 16 + l15) * HD;
#pragma unroll
    for (int c = 0; c < 4; c++)
      qf[c] = *(const bf16x8a*)(qrow + c * 32 + quad * 8);
  }

  f32x4 o[8];
#pragma unroll
  for (int i = 0; i < 8; i++) { f32x4 z = {0.f,0.f,0.f,0.f}; o[i] = z; }
  float m_i[4], l_i[4];
#pragma unroll
  for (int r = 0; r < 4; r++) { m_i[r] = -1e30f; l_i[r] = 0.0f; }

  const float scale = 0.08838834764831845f;   // 1/sqrt(128)

  for (int k0 = 0; k0 <= q0; k0 += 64) {
    __syncthreads();
    // stage K tile [64][128] -> stride KT_STR (16B chunks)
    for (int s2 = tid; s2 < 1024; s2 += 256) {
      int rr = s2 >> 4, cc = (s2 & 15) * 8;
      *(bf16x8a*)&Kt[rr * KT_STR + cc] =
          *(const bf16x8a*)(Kg + (size_t)(k0 + rr) * HD + cc);
    }
    // stage V transposed: Vt[hd][key]
    for (int e = tid; e < 64 * HD; e += 256) {
      int key = e >> 7, hd = e & 127;
      Vt[hd * V_STR + key] = Vg[(size_t)(k0 + key) * HD + hd];
    }
    __syncthreads();

    // S = Q K^T  (4 key-subtiles x 4 hd-chunks)
    f32x4 st[4];
#pragma unroll
    for (int nt = 0; nt < 4; nt++) {
      f32x4 z = {0.f,0.f,0.f,0.f}; st[nt] = z;
#pragma unroll
      for (int c = 0; c < 4; c++) {
        bf16x8 kf = *(const bf16x8a*)&Kt[(nt * 16 + l15) * KT_STR + c * 32 + quad * 8];
        st[nt] = mfma_bf16(qf[c], kf, st[nt]);
      }
    }
    // scale + causal mask (diagonal tile only)
    bool diag = (k0 == q0);
#pragma unroll
    for (int nt = 0; nt < 4; nt++)
#pragma unroll
      for (int r = 0; r < 4; r++) {
        float v = st[nt][r] * scale;
        if (diag) {
          int qr = w * 16 + quad * 4 + r;
          int kc = nt * 16 + l15;
          if (kc > qr) v += -1e9f;
        }
        st[nt][r] = v;
      }
    // online softmax; rows live in (quad, reg), cols across 16 lanes
    float alpha[4];
#pragma unroll
    for (int r = 0; r < 4; r++) {
      float mx = fmaxf(fmaxf(st[0][r], st[1][r]), fmaxf(st[2][r], st[3][r]));
#pragma unroll
      for (int off = 1; off < 16; off <<= 1)
        mx = fmaxf(mx, __shfl_xor(mx, off, 16));
      float mnew = fmaxf(m_i[r], mx);
      alpha[r] = __expf(m_i[r] - mnew);
      m_i[r] = mnew;
      float rowsum = 0.0f;
#pragma unroll
      for (int nt = 0; nt < 4; nt++) {
        float p = __expf(st[nt][r] - mnew);
        p = (float)(bf16_t)p;       // match what MFMA will consume
        st[nt][r] = p;
        rowsum += p;
      }
#pragma unroll
      for (int off = 1; off < 16; off <<= 1)
        rowsum += __shfl_xor(rowsum, off, 16);
      l_i[r] = l_i[r] * alpha[r] + rowsum;
    }
    // write P (C-layout -> LDS), rescale O, then O += P*V
#pragma unroll
    for (int nt = 0; nt < 4; nt++)
#pragma unroll
      for (int r = 0; r < 4; r++)
        Pt[(w * 16 + quad * 4 + r) * P_STR + nt * 16 + l15] = (bf16_t)st[nt][r];
#pragma unroll
    for (int t8 = 0; t8 < 8; t8++)
#pragma unroll
      for (int r = 0; r < 4; r++)
        o[t8][r] *= alpha[r];
#pragma unroll
    for (int kc = 0; kc < 2; kc++) {
      bf16x8 pf = *(const bf16x8a*)&Pt[(w * 16 + l15) * P_STR + kc * 32 + quad * 8];
#pragma unroll
      for (int t8 = 0; t8 < 8; t8++) {
        bf16x8 vf = *(const bf16x8a*)&Vt[(t8 * 16 + l15) * V_STR + kc * 32 + quad * 8];
        o[t8] = mfma_bf16(pf, vf, o[t8]);
      }
    }
  }

  const int b = bh >> 4, h = bh & 15;
#pragma unroll
  for (int t8 = 0; t8 < 8; t8++)
#pragma unroll
    for (int r = 0; r < 4; r++) {
      int qr = q0 + w * 16 + quad * 4 + r;
      int col = h * HD + t8 * 16 + l15;
      float v = o[t8][r] / l_i[r];
      attnB[(size_t)(b * S_LEN + qr) * HDIM + col] = (bf16_t)v;
    }
}

// ---------------- launcher ----------------
extern "C" void kernel_launch(void* const* d_in, const int* in_sizes, int n_in,
                              void* d_out, int out_size, void* d_ws, size_t ws_size,
                              hipStream_t stream) {
  const float* hs    = (const float*)d_in[0];
  const float* lte   = (const float*)d_in[1];
  const float* Wq    = (const float*)d_in[2];
  const float* Wk    = (const float*)d_in[3];
  const float* Wv    = (const float*)d_in[4];
  const float* Wo    = (const float*)d_in[5];
  const float* Wts   = (const float*)d_in[6];
  const float* tsw   = (const float*)d_in[7];
  const float* Worig = (const float*)d_in[8];
  float* out = (float*)d_out;

  char* p = (char*)d_ws;
  bf16_t* hsB   = (bf16_t*)(p);                    // 16,777,216  [4096][2048]
  bf16_t* wT    = (bf16_t*)(p + 16777216);         //  8,388,608  reused per GEMM
  float*  tsB   = (float*)(p + 25165824);          //  8,388,608  [4096][512]
  bf16_t* tsf   = (bf16_t*)(p + 33554432);         //  4,194,304  [4096][512]
  bf16_t* qkadd = (bf16_t*)(p + 37748736);         // 33,554,432  [4096][4096]
  bf16_t* attnB = qkadd;                           // alias; qkadd dead by attention
  bf16_t* qbuf  = (bf16_t*)(p + 71303168);         // 16,777,216  [32][2048][128]
  bf16_t* kbuf  = (bf16_t*)(p + 88080384);         // 16,777,216
  bf16_t* vbuf  = (bf16_t*)(p + 104857600);        // 16,777,216 -> total 121,634,816

  // 1. hidden_states -> bf16
  k_cvt<<<8192, 256, 0, stream>>>(hs, hsB, BROWS * HDIM);
  // 2. ts = hs @ Wts  (fp32 out)
  k_transpose<<<dim3(16, 64), dim3(32, 8), 0, stream>>>(Wts, wT, 2048, 512, 512);
  k_gemm<0><<<dim3(4, 32), 256, 0, stream>>>(hsB, wT, tsB, nullptr, nullptr,
                                             4096, 512, 2048, 0, 0);
  // 3. blend + rmsnorm + top-k threshold + relu
  k_tsproc<<<4096, 256, 0, stream>>>(tsB, lte, tsw, tsf);
  // 4. qk_add = ts_filtered @ Worig[:, :4096]  (bf16 out)
  k_transpose<<<dim3(128, 16), dim3(32, 8), 0, stream>>>(Worig, wT, 512, 4096, 6144);
  k_gemm<1><<<dim3(32, 32), 256, 0, stream>>>(tsf, wT, nullptr, qkadd, nullptr,
                                              4096, 4096, 512, 0, 0);
  // 5. q/k/v projections with additive bias, permuted bf16 stores
  k_transpose<<<dim3(64, 64), dim3(32, 8), 0, stream>>>(Wq, wT, 2048, 2048, 2048);
  k_gemm<2><<<dim3(16, 32), 256, 0, stream>>>(hsB, wT, nullptr, qbuf, qkadd,
                                              4096, 2048, 2048, 4096, 0);
  k_transpose<<<dim3(64, 64), dim3(32, 8), 0, stream>>>(Wk, wT, 2048, 2048, 2048);
  k_gemm<2><<<dim3(16, 32), 256, 0, stream>>>(hsB, wT, nullptr, kbuf, qkadd,
                                              4096, 2048, 2048, 4096, 2048);
  k_transpose<<<dim3(64, 64), dim3(32, 8), 0, stream>>>(Wv, wT, 2048, 2048, 2048);
  k_gemm<2><<<dim3(16, 32), 256, 0, stream>>>(hsB, wT, nullptr, vbuf, qkadd,
                                              4096, 2048, 2048, 4096, 2048);
  // 6. RoPE on q and k
  k_rope<<<16384, 256, 0, stream>>>(qbuf);
  k_rope<<<16384, 256, 0, stream>>>(kbuf);
  // 7. causal flash attention -> attnB [4096][2048] bf16
  k_attn<<<dim3(32, 32), 256, 0, stream>>>(qbuf, kbuf, vbuf, attnB);
  // 8. out = attn @ Wo  (fp32)
  k_transpose<<<dim3(64, 64), dim3(32, 8), 0, stream>>>(Wo, wT, 2048, 2048, 2048);
  k_gemm<0><<<dim3(16, 32), 256, 0, stream>>>(attnB, wT, out, nullptr, nullptr,
                                              4096, 2048, 2048, 0, 0);
}

// Round 2
// 770.554 us; speedup vs baseline: 1.0823x; 1.0823x over previous
//
#include <hip/hip_runtime.h>
#include <cstdint>

// ---------------- types ----------------
typedef __bf16 bf16_t;
typedef __bf16 bf16x8 __attribute__((ext_vector_type(8)));
typedef __bf16 bf16x4 __attribute__((ext_vector_type(4)));
typedef float  f32x4  __attribute__((ext_vector_type(4)));
typedef bf16x8 __attribute__((may_alias)) bf16x8a;
typedef bf16x4 __attribute__((may_alias)) bf16x4a;
typedef f32x4  __attribute__((may_alias)) f32x4a;

#define S_LEN 2048
#define HDIM  2048
#define NHEAD 16
#define HD    128
#define TSD   512
#define BROWS 4096   // B * S
#define KIDX  459    // K_IDX - 1

__device__ __forceinline__ f32x4 mfma_bf16(bf16x8 a, bf16x8 b, f32x4 c) {
  return __builtin_amdgcn_mfma_f32_16x16x32_bf16(a, b, c, 0, 0, 0);
}

__device__ __forceinline__ void gld_lds16(const bf16_t* g, bf16_t* l) {
  __builtin_amdgcn_global_load_lds(
      (__attribute__((address_space(1))) void*)(void*)const_cast<bf16_t*>(g),
      (__attribute__((address_space(3))) void*)(void*)(l), 16, 0, 0);
}

// ---------------- elementwise convert fp32 -> bf16 ----------------
__global__ void k_cvt(const float* __restrict__ in, bf16_t* __restrict__ out, int n) {
  int i = (blockIdx.x * 256 + threadIdx.x) * 4;
  if (i >= n) return;
  f32x4 v = *(const f32x4a*)(in + i);
  bf16x4 o = { (bf16_t)v.x, (bf16_t)v.y, (bf16_t)v.z, (bf16_t)v.w };
  *(bf16x4a*)(out + i) = o;
}

// ---------------- transpose + convert: out[c][r] = in[r][c] ----------------
__global__ void k_transpose(const float* __restrict__ in, bf16_t* __restrict__ out,
                            int R, int C, int ldin) {
  __shared__ float tile[32][33];
  int c0 = blockIdx.x * 32, r0 = blockIdx.y * 32;
  int tx = threadIdx.x, ty = threadIdx.y;
  for (int i = ty; i < 32; i += 8)
    tile[i][tx] = in[(size_t)(r0 + i) * ldin + c0 + tx];
  __syncthreads();
  for (int i = ty; i < 32; i += 8)
    out[(size_t)(c0 + i) * R + r0 + tx] = (bf16_t)tile[tx][i];
}

// ---------------- bf16 transpose: vbuf [bh][s][d] -> vtb [bh][d][s] ----------------
__global__ void k_vtrans(const bf16_t* __restrict__ in, bf16_t* __restrict__ out) {
  __shared__ bf16_t t[64][72];
  int s0 = blockIdx.x * 64, d0 = blockIdx.y * 64, bh = blockIdx.z;
  const bf16_t* src = in + (size_t)bh * S_LEN * HD;
  bf16_t* dst = out + (size_t)bh * HD * S_LEN;
  int tid = threadIdx.x;
  for (int g = tid; g < 512; g += 256) {
    int r = g >> 3, cc = g & 7;
    *(bf16x8a*)&t[r][cc * 8] = *(const bf16x8a*)(src + (size_t)(s0 + r) * HD + d0 + cc * 8);
  }
  __syncthreads();
  for (int g = tid; g < 512; g += 256) {
    int dr = g >> 3, sc = g & 7;
    bf16x8 v;
#pragma unroll
    for (int j = 0; j < 8; j++) v[j] = t[sc * 8 + j][dr];
    *(bf16x8a*)(dst + (size_t)(d0 + dr) * S_LEN + s0 + sc * 8) = v;
  }
}

// ---------------- bf16 MFMA GEMM, B pre-transposed (N x K) ----------------
template<int MODE>
__global__ __launch_bounds__(256)
void k_gemm(const bf16_t* __restrict__ A, const bf16_t* __restrict__ Bt,
            float* __restrict__ outF, bf16_t* __restrict__ outB,
            const bf16_t* __restrict__ addend, int M, int N, int K,
            int addLd, int addCol)
{
  __shared__ __align__(16) bf16_t As[128 * 32];
  __shared__ __align__(16) bf16_t Bs[128 * 32];
  const int tid  = threadIdx.x;
  const int lane = tid & 63, w = tid >> 6;
  const int quad = lane >> 4, l15 = lane & 15;
  const int m0 = blockIdx.y * 128, n0 = blockIdx.x * 128;
  const int wm = (w >> 1) * 64, wn = (w & 1) * 64;

  f32x4 acc[4][4];
#pragma unroll
  for (int i = 0; i < 4; i++)
#pragma unroll
    for (int j = 0; j < 4; j++) { f32x4 z = {0.f,0.f,0.f,0.f}; acc[i][j] = z; }

  const int srow = w * 16 + (lane >> 2);
  const int scol = (lane & 3) * 8;

  for (int k0 = 0; k0 < K; k0 += 32) {
    __syncthreads();
    gld_lds16(A  + (size_t)(m0 +      srow) * K + k0 + scol, As + (size_t)w * 512);
    gld_lds16(A  + (size_t)(m0 + 64 + srow) * K + k0 + scol, As + (size_t)(4 + w) * 512);
    gld_lds16(Bt + (size_t)(n0 +      srow) * K + k0 + scol, Bs + (size_t)w * 512);
    gld_lds16(Bt + (size_t)(n0 + 64 + srow) * K + k0 + scol, Bs + (size_t)(4 + w) * 512);
    __syncthreads();
    bf16x8 af[4], bv[4];
#pragma unroll
    for (int i = 0; i < 4; i++)
      af[i] = *(const bf16x8a*)&As[(wm + i * 16 + l15) * 32 + quad * 8];
#pragma unroll
    for (int j = 0; j < 4; j++)
      bv[j] = *(const bf16x8a*)&Bs[(wn + j * 16 + l15) * 32 + quad * 8];
#pragma unroll
    for (int i = 0; i < 4; i++)
#pragma unroll
      for (int j = 0; j < 4; j++)
        acc[i][j] = mfma_bf16(af[i], bv[j], acc[i][j]);
  }

#pragma unroll
  for (int i = 0; i < 4; i++)
#pragma unroll
    for (int j = 0; j < 4; j++)
#pragma unroll
      for (int r = 0; r < 4; r++) {
        int row = m0 + wm + i * 16 + quad * 4 + r;
        int col = n0 + wn + j * 16 + l15;
        float v = acc[i][j][r];
        if (MODE == 0) {
          outF[(size_t)row * N + col] = v;
        } else if (MODE == 1) {
          outB[(size_t)row * N + col] = (bf16_t)v;
        } else {
          v += (float)addend[(size_t)row * addLd + addCol + col];
          int s = row & (S_LEN - 1), b = row >> 11;
          int h = col >> 7, d = col & (HD - 1);
          outB[(((size_t)(b * NHEAD + h) * S_LEN) + s) * HD + d] = (bf16_t)v;
        }
      }
}

// ---------------- blend + rmsnorm + kth-threshold + relu ----------------
__global__ __launch_bounds__(256)
void k_tsproc(const float* __restrict__ ts, const float* __restrict__ lte,
              const float* __restrict__ wn, bf16_t* __restrict__ tsf)
{
  __shared__ float sv[TSD];
  __shared__ float red[4];
  int row = blockIdx.x;
  int t = threadIdx.x;
  const float* tr = ts  + (size_t)row * TSD;
  const float* lr = lte + (size_t)row * TSD;
  float v0 = 0.5f * tr[t] + 0.5f * lr[t];
  float v1 = 0.5f * tr[t + 256] + 0.5f * lr[t + 256];
  float ss = v0 * v0 + v1 * v1;
#pragma unroll
  for (int o = 32; o > 0; o >>= 1) ss += __shfl_down(ss, o);
  int lane = t & 63, wv = t >> 6;
  if (lane == 0) red[wv] = ss;
  __syncthreads();
  float tot = red[0] + red[1] + red[2] + red[3];
  float scl = rsqrtf(tot * (1.0f / TSD) + 1e-6f);
  float n0 = v0 * scl * wn[t];
  float n1 = v1 * scl * wn[t + 256];
  sv[t] = n0; sv[t + 256] = n1;
  __syncthreads();
  for (int k = 2; k <= TSD; k <<= 1) {
    for (int j = k >> 1; j > 0; j >>= 1) {
#pragma unroll
      for (int u = 0; u < 2; u++) {
        int idx = t + u * 256;
        int ixj = idx ^ j;
        if (ixj > idx) {
          float a = sv[idx], b = sv[ixj];
          bool up = ((idx & k) == 0);
          if ((a > b) == up) { sv[idx] = b; sv[ixj] = a; }
        }
      }
      __syncthreads();
    }
  }
  float kth = sv[KIDX];
  tsf[(size_t)row * TSD + t]       = (bf16_t)fmaxf(n0 - kth, 0.0f);
  tsf[(size_t)row * TSD + t + 256] = (bf16_t)fmaxf(n1 - kth, 0.0f);
}

// ---------------- RoPE in place on [B*NH, S, HD] bf16 ----------------
__global__ void k_rope(bf16_t* __restrict__ x) {
  int gid = blockIdx.x * 256 + threadIdx.x;
  int d = gid & 63;
  int rowi = gid >> 6;
  int s = rowi & (S_LEN - 1);
  bf16_t* p = x + (size_t)rowi * HD;
  float inv = powf(10000.0f, (float)(-2 * d) * (1.0f / 128.0f));
  float ang = (float)s * inv;
  float sn, c;
  sincosf(ang, &sn, &c);
  float x0 = (float)p[d], x1 = (float)p[d + 64];
  p[d]      = (bf16_t)(x0 * c - x1 * sn);
  p[d + 64] = (bf16_t)(x1 * c + x0 * sn);
}

// ---------------- flash attention v2 (causal) ----------------
// Q-tile 128 (wave owns 32 rows), K-tile 64. V pre-transposed [bh][d][s].
// K/V staged via global_load_lds with XOR-swizzled granules (bank-balanced,
// unpadded LDS). P in its own buffer (per-wave private -> no extra barrier).
__global__ __launch_bounds__(256, 3)
void k_attn(const bf16_t* __restrict__ qb, const bf16_t* __restrict__ kb,
            const bf16_t* __restrict__ vtb, bf16_t* __restrict__ attnB)
{
  __shared__ __align__(16) bf16_t Kt[64 * 128];   // [key][d], swizzled granules
  __shared__ __align__(16) bf16_t Vt[128 * 64];   // [d][key], swizzled granules
  __shared__ __align__(16) bf16_t Pt[128 * 72];   // [qrow][key], stride 72

  const int bid = blockIdx.x;
  const int bh = bid >> 4;
  static const int qmap[16] = {15,0,14,1,13,2,12,3,11,4,10,5,9,6,8,7};
  const int q0 = qmap[(bid + (bid >> 8)) & 15] * 128;

  const int tid = threadIdx.x;
  const int lane = tid & 63, w = tid >> 6;
  const int quad = lane >> 4, l15 = lane & 15;

  const bf16_t* Q  = qb  + (size_t)bh * S_LEN * HD;
  const bf16_t* Kg = kb  + (size_t)bh * S_LEN * HD;
  const bf16_t* Vg = vtb + (size_t)bh * HD * S_LEN;   // [d][s]

  // Q fragments: wave w owns rows q0 + w*32 .. +31 (2 sub-tiles of 16)
  bf16x8 qf[2][4];
#pragma unroll
  for (int mi = 0; mi < 2; mi++) {
    const bf16_t* qrow = Q + (size_t)(q0 + w * 32 + mi * 16 + l15) * HD;
#pragma unroll
    for (int c = 0; c < 4; c++)
      qf[mi][c] = *(const bf16x8a*)(qrow + c * 32 + quad * 8);
  }

  // fragment base pointers (swizzle folded in)
  const bf16_t* kfp[4];
#pragma unroll
  for (int c = 0; c < 4; c++)
    kfp[c] = Kt + l15 * 128 + (((c * 4 + quad) ^ (l15 & 7)) * 8);
  const bf16_t* vfp[2];
#pragma unroll
  for (int kc = 0; kc < 2; kc++)
    vfp[kc] = Vt + l15 * 64 + (((kc * 4 + quad) ^ (l15 & 7)) * 8);

  // staging lane constants
  const int vD  = w * 32 + (lane >> 3);
  const int vCc = ((lane & 7) ^ ((lane >> 3) & 7)) * 8;

  f32x4 o[2][8];
#pragma unroll
  for (int mi = 0; mi < 2; mi++)
#pragma unroll
    for (int t8 = 0; t8 < 8; t8++) { f32x4 z = {0.f,0.f,0.f,0.f}; o[mi][t8] = z; }
  float m_i[2][4], l_i[2][4];
#pragma unroll
  for (int mi = 0; mi < 2; mi++)
#pragma unroll
    for (int r = 0; r < 4; r++) { m_i[mi][r] = -1e30f; l_i[mi][r] = 0.0f; }

  const float scale = 0.08838834764831845f;   // 1/sqrt(128)
  const int kEnd = q0 + 64;

  for (int k0 = 0; k0 <= kEnd; k0 += 64) {
    __syncthreads();    // prior-iter Kt/Vt reads complete
    // stage K tile [64][128]: wave w -> rows w*16..+15
#pragma unroll
    for (int t = 0; t < 4; t++) {
      int r  = w * 16 + t * 4 + quad;
      int cc = l15 ^ ((t * 4 + quad) & 7);
      gld_lds16(Kg + (size_t)(k0 + r) * HD + cc * 8, Kt + w * 2048 + t * 512);
    }
    // stage V^T tile [128][64]: wave w -> d rows w*32..+31
#pragma unroll
    for (int t = 0; t < 4; t++)
      gld_lds16(Vg + (size_t)(vD + t * 8) * S_LEN + k0 + vCc, Vt + w * 2048 + t * 512);
    __syncthreads();

    // S = Q K^T
    f32x4 st[2][4];
#pragma unroll
    for (int mi = 0; mi < 2; mi++)
#pragma unroll
      for (int nt = 0; nt < 4; nt++) { f32x4 z = {0.f,0.f,0.f,0.f}; st[mi][nt] = z; }
#pragma unroll
    for (int nt = 0; nt < 4; nt++)
#pragma unroll
      for (int c = 0; c < 4; c++) {
        bf16x8 kf = *(const bf16x8a*)(kfp[c] + nt * 2048);
        st[0][nt] = mfma_bf16(qf[0][c], kf, st[0][nt]);
        st[1][nt] = mfma_bf16(qf[1][c], kf, st[1][nt]);
      }

    // scale + causal mask + online softmax (per 16-row sub-tile)
    float alpha[2][4];
#pragma unroll
    for (int mi = 0; mi < 2; mi++) {
      const int rowBase = q0 + w * 32 + mi * 16;
      const bool tileMask = (k0 + 63) > rowBase;
#pragma unroll
      for (int nt = 0; nt < 4; nt++)
#pragma unroll
        for (int r = 0; r < 4; r++) {
          float v = st[mi][nt][r] * scale;
          if (tileMask) {
            int row = rowBase + quad * 4 + r;
            int col = k0 + nt * 16 + l15;
            if (col > row) v = -1e9f;
          }
          st[mi][nt][r] = v;
        }
#pragma unroll
      for (int r = 0; r < 4; r++) {
        float mx = fmaxf(fmaxf(st[mi][0][r], st[mi][1][r]),
                         fmaxf(st[mi][2][r], st[mi][3][r]));
#pragma unroll
        for (int off = 1; off < 16; off <<= 1)
          mx = fmaxf(mx, __shfl_xor(mx, off, 16));
        float mnew = fmaxf(m_i[mi][r], mx);
        alpha[mi][r] = __expf(m_i[mi][r] - mnew);
        m_i[mi][r] = mnew;
        float rowsum = 0.0f;
#pragma unroll
        for (int nt = 0; nt < 4; nt++) {
          float pv = __expf(st[mi][nt][r] - mnew);
          pv = (float)(bf16_t)pv;
          st[mi][nt][r] = pv;
          rowsum += pv;
        }
#pragma unroll
        for (int off = 1; off < 16; off <<= 1)
          rowsum += __shfl_xor(rowsum, off, 16);
        l_i[mi][r] = l_i[mi][r] * alpha[mi][r] + rowsum;
      }
    }

    // write P (per-wave private rows w*32..+31)
#pragma unroll
    for (int mi = 0; mi < 2; mi++)
#pragma unroll
      for (int nt = 0; nt < 4; nt++)
#pragma unroll
        for (int r = 0; r < 4; r++)
          Pt[(w * 32 + mi * 16 + quad * 4 + r) * 72 + nt * 16 + l15] =
              (bf16_t)st[mi][nt][r];

    // rescale O
#pragma unroll
    for (int mi = 0; mi < 2; mi++)
#pragma unroll
      for (int t8 = 0; t8 < 8; t8++)
#pragma unroll
        for (int r = 0; r < 4; r++)
          o[mi][t8][r] *= alpha[mi][r];

    // O += P * V
#pragma unroll
    for (int kc = 0; kc < 2; kc++) {
      bf16x8 pf0 = *(const bf16x8a*)(Pt + (w * 32 +      l15) * 72 + kc * 32 + quad * 8);
      bf16x8 pf1 = *(const bf16x8a*)(Pt + (w * 32 + 16 + l15) * 72 + kc * 32 + quad * 8);
#pragma unroll
      for (int t8 = 0; t8 < 8; t8++) {
        bf16x8 vf = *(const bf16x8a*)(vfp[kc] + t8 * 1024);
        o[0][t8] = mfma_bf16(pf0, vf, o[0][t8]);
        o[1][t8] = mfma_bf16(pf1, vf, o[1][t8]);
      }
    }
  }

  const int b = bh >> 4, h = bh & 15;
#pragma unroll
  for (int mi = 0; mi < 2; mi++)
#pragma unroll
    for (int r = 0; r < 4; r++) {
      float rl = 1.0f / l_i[mi][r];
      int qr = q0 + w * 32 + mi * 16 + quad * 4 + r;
#pragma unroll
      for (int t8 = 0; t8 < 8; t8++) {
        int col = h * HD + t8 * 16 + l15;
        attnB[(size_t)(b * S_LEN + qr) * HDIM + col] = (bf16_t)(o[mi][t8][r] * rl);
      }
    }
}

// ---------------- launcher ----------------
extern "C" void kernel_launch(void* const* d_in, const int* in_sizes, int n_in,
                              void* d_out, int out_size, void* d_ws, size_t ws_size,
                              hipStream_t stream) {
  const float* hs    = (const float*)d_in[0];
  const float* lte   = (const float*)d_in[1];
  const float* Wq    = (const float*)d_in[2];
  const float* Wk    = (const float*)d_in[3];
  const float* Wv    = (const float*)d_in[4];
  const float* Wo    = (const float*)d_in[5];
  const float* Wts   = (const float*)d_in[6];
  const float* tsw   = (const float*)d_in[7];
  const float* Worig = (const float*)d_in[8];
  float* out = (float*)d_out;

  char* p = (char*)d_ws;
  bf16_t* hsB   = (bf16_t*)(p);                    // 16 MB [4096][2048]
  bf16_t* wT    = (bf16_t*)(p + 16777216);         //  8 MB reused per GEMM
  float*  tsB   = (float*)(p + 25165824);          //  8 MB [4096][512]
  bf16_t* tsf   = (bf16_t*)(p + 33554432);         //  4 MB [4096][512]
  bf16_t* qkadd = (bf16_t*)(p + 37748736);         // 32 MB [4096][4096] (dead after QKV)
  bf16_t* attnB = qkadd;                           // 16 MB alias (lower half)
  bf16_t* vtb   = (bf16_t*)(p + 54525952);         // 16 MB alias (upper half) [bh][d][s]
  bf16_t* qbuf  = (bf16_t*)(p + 71303168);         // 16 MB [32][2048][128]
  bf16_t* kbuf  = (bf16_t*)(p + 88080384);         // 16 MB
  bf16_t* vbuf  = (bf16_t*)(p + 104857600);        // 16 MB -> total 121,634,816

  k_cvt<<<8192, 256, 0, stream>>>(hs, hsB, BROWS * HDIM);
  k_transpose<<<dim3(16, 64), dim3(32, 8), 0, stream>>>(Wts, wT, 2048, 512, 512);
  k_gemm<0><<<dim3(4, 32), 256, 0, stream>>>(hsB, wT, tsB, nullptr, nullptr,
                                             4096, 512, 2048, 0, 0);
  k_tsproc<<<4096, 256, 0, stream>>>(tsB, lte, tsw, tsf);
  k_transpose<<<dim3(128, 16), dim3(32, 8), 0, stream>>>(Worig, wT, 512, 4096, 6144);
  k_gemm<1><<<dim3(32, 32), 256, 0, stream>>>(tsf, wT, nullptr, qkadd, nullptr,
                                              4096, 4096, 512, 0, 0);
  k_transpose<<<dim3(64, 64), dim3(32, 8), 0, stream>>>(Wq, wT, 2048, 2048, 2048);
  k_gemm<2><<<dim3(16, 32), 256, 0, stream>>>(hsB, wT, nullptr, qbuf, qkadd,
                                              4096, 2048, 2048, 4096, 0);
  k_transpose<<<dim3(64, 64), dim3(32, 8), 0, stream>>>(Wk, wT, 2048, 2048, 2048);
  k_gemm<2><<<dim3(16, 32), 256, 0, stream>>>(hsB, wT, nullptr, kbuf, qkadd,
                                              4096, 2048, 2048, 4096, 2048);
  k_transpose<<<dim3(64, 64), dim3(32, 8), 0, stream>>>(Wv, wT, 2048, 2048, 2048);
  k_gemm<2><<<dim3(16, 32), 256, 0, stream>>>(hsB, wT, nullptr, vbuf, qkadd,
                                              4096, 2048, 2048, 4096, 2048);
  k_rope<<<16384, 256, 0, stream>>>(qbuf);
  k_rope<<<16384, 256, 0, stream>>>(kbuf);
  k_vtrans<<<dim3(32, 2, 32), 256, 0, stream>>>(vbuf, vtb);
  k_transpose<<<dim3(64, 64), dim3(32, 8), 0, stream>>>(Wo, wT, 2048, 2048, 2048);
  k_attn<<<512, 256, 0, stream>>>(qbuf, kbuf, vtb, attnB);
  k_gemm<0><<<dim3(16, 32), 256, 0, stream>>>(attnB, wT, out, nullptr, nullptr,
                                              4096, 2048, 2048, 0, 0);
}

// Round 3
// 718.997 us; speedup vs baseline: 1.1599x; 1.0717x over previous
//
#include <hip/hip_runtime.h>
#include <cstdint>

// ---------------- types ----------------
typedef __bf16 bf16_t;
typedef __bf16 bf16x8 __attribute__((ext_vector_type(8)));
typedef __bf16 bf16x4 __attribute__((ext_vector_type(4)));
typedef float  f32x4  __attribute__((ext_vector_type(4)));
typedef bf16x8 __attribute__((may_alias)) bf16x8a;
typedef bf16x4 __attribute__((may_alias)) bf16x4a;
typedef f32x4  __attribute__((may_alias)) f32x4a;

#define S_LEN 2048
#define HDIM  2048
#define NHEAD 16
#define HD    128
#define TSD   512
#define BROWS 4096   // B * S
#define KIDX  459    // K_IDX - 1

__device__ __forceinline__ f32x4 mfma_bf16(bf16x8 a, bf16x8 b, f32x4 c) {
  return __builtin_amdgcn_mfma_f32_16x16x32_bf16(a, b, c, 0, 0, 0);
}

__device__ __forceinline__ void gld_lds16(const bf16_t* g, bf16_t* l) {
  __builtin_amdgcn_global_load_lds(
      (__attribute__((address_space(1))) void*)(void*)const_cast<bf16_t*>(g),
      (__attribute__((address_space(3))) void*)(void*)(l), 16, 0, 0);
}

// ---------------- elementwise convert fp32 -> bf16 ----------------
__global__ void k_cvt(const float* __restrict__ in, bf16_t* __restrict__ out, int n) {
  int i = (blockIdx.x * 256 + threadIdx.x) * 4;
  if (i >= n) return;
  f32x4 v = *(const f32x4a*)(in + i);
  bf16x4 o = { (bf16_t)v.x, (bf16_t)v.y, (bf16_t)v.z, (bf16_t)v.w };
  *(bf16x4a*)(out + i) = o;
}

// ---------------- transpose + convert: out[c][r] = in[r][c] ----------------
__global__ void k_transpose(const float* __restrict__ in, bf16_t* __restrict__ out,
                            int R, int C, int ldin) {
  __shared__ float tile[32][33];
  int c0 = blockIdx.x * 32, r0 = blockIdx.y * 32;
  int tx = threadIdx.x, ty = threadIdx.y;
  for (int i = ty; i < 32; i += 8)
    tile[i][tx] = in[(size_t)(r0 + i) * ldin + c0 + tx];
  __syncthreads();
  for (int i = ty; i < 32; i += 8)
    out[(size_t)(c0 + i) * R + r0 + tx] = (bf16_t)tile[tx][i];
}

// ---------------- bf16 transpose: vbuf [bh][s][d] -> vtb [bh][d][s] ----------------
__global__ void k_vtrans(const bf16_t* __restrict__ in, bf16_t* __restrict__ out) {
  __shared__ bf16_t t[64][72];
  int s0 = blockIdx.x * 64, d0 = blockIdx.y * 64, bh = blockIdx.z;
  const bf16_t* src = in + (size_t)bh * S_LEN * HD;
  bf16_t* dst = out + (size_t)bh * HD * S_LEN;
  int tid = threadIdx.x;
  for (int g = tid; g < 512; g += 256) {
    int r = g >> 3, cc = g & 7;
    *(bf16x8a*)&t[r][cc * 8] = *(const bf16x8a*)(src + (size_t)(s0 + r) * HD + d0 + cc * 8);
  }
  __syncthreads();
  for (int g = tid; g < 512; g += 256) {
    int dr = g >> 3, sc = g & 7;
    bf16x8 v;
#pragma unroll
    for (int j = 0; j < 8; j++) v[j] = t[sc * 8 + j][dr];
    *(bf16x8a*)(dst + (size_t)(d0 + dr) * S_LEN + s0 + sc * 8) = v;
  }
}

// ---------------- bf16 MFMA GEMM, B pre-transposed (N x K) ----------------
template<int MODE>
__global__ __launch_bounds__(256)
void k_gemm(const bf16_t* __restrict__ A, const bf16_t* __restrict__ Bt,
            float* __restrict__ outF, bf16_t* __restrict__ outB,
            const bf16_t* __restrict__ addend, int M, int N, int K,
            int addLd, int addCol)
{
  __shared__ __align__(16) bf16_t As[128 * 32];
  __shared__ __align__(16) bf16_t Bs[128 * 32];
  const int tid  = threadIdx.x;
  const int lane = tid & 63, w = tid >> 6;
  const int quad = lane >> 4, l15 = lane & 15;
  const int m0 = blockIdx.y * 128, n0 = blockIdx.x * 128;
  const int wm = (w >> 1) * 64, wn = (w & 1) * 64;

  f32x4 acc[4][4];
#pragma unroll
  for (int i = 0; i < 4; i++)
#pragma unroll
    for (int j = 0; j < 4; j++) { f32x4 z = {0.f,0.f,0.f,0.f}; acc[i][j] = z; }

  const int srow = w * 16 + (lane >> 2);
  const int scol = (lane & 3) * 8;

  for (int k0 = 0; k0 < K; k0 += 32) {
    __syncthreads();
    gld_lds16(A  + (size_t)(m0 +      srow) * K + k0 + scol, As + (size_t)w * 512);
    gld_lds16(A  + (size_t)(m0 + 64 + srow) * K + k0 + scol, As + (size_t)(4 + w) * 512);
    gld_lds16(Bt + (size_t)(n0 +      srow) * K + k0 + scol, Bs + (size_t)w * 512);
    gld_lds16(Bt + (size_t)(n0 + 64 + srow) * K + k0 + scol, Bs + (size_t)(4 + w) * 512);
    __syncthreads();
    bf16x8 af[4], bv[4];
#pragma unroll
    for (int i = 0; i < 4; i++)
      af[i] = *(const bf16x8a*)&As[(wm + i * 16 + l15) * 32 + quad * 8];
#pragma unroll
    for (int j = 0; j < 4; j++)
      bv[j] = *(const bf16x8a*)&Bs[(wn + j * 16 + l15) * 32 + quad * 8];
#pragma unroll
    for (int i = 0; i < 4; i++)
#pragma unroll
      for (int j = 0; j < 4; j++)
        acc[i][j] = mfma_bf16(af[i], bv[j], acc[i][j]);
  }

#pragma unroll
  for (int i = 0; i < 4; i++)
#pragma unroll
    for (int j = 0; j < 4; j++)
#pragma unroll
      for (int r = 0; r < 4; r++) {
        int row = m0 + wm + i * 16 + quad * 4 + r;
        int col = n0 + wn + j * 16 + l15;
        float v = acc[i][j][r];
        if (MODE == 0) {
          outF[(size_t)row * N + col] = v;
        } else if (MODE == 1) {
          outB[(size_t)row * N + col] = (bf16_t)v;
        } else {
          v += (float)addend[(size_t)row * addLd + addCol + col];
          int s = row & (S_LEN - 1), b = row >> 11;
          int h = col >> 7, d = col & (HD - 1);
          outB[(((size_t)(b * NHEAD + h) * S_LEN) + s) * HD + d] = (bf16_t)v;
        }
      }
}

// ---------------- blend + rmsnorm + kth-threshold + relu ----------------
__global__ __launch_bounds__(256)
void k_tsproc(const float* __restrict__ ts, const float* __restrict__ lte,
              const float* __restrict__ wn, bf16_t* __restrict__ tsf)
{
  __shared__ float sv[TSD];
  __shared__ float red[4];
  int row = blockIdx.x;
  int t = threadIdx.x;
  const float* tr = ts  + (size_t)row * TSD;
  const float* lr = lte + (size_t)row * TSD;
  float v0 = 0.5f * tr[t] + 0.5f * lr[t];
  float v1 = 0.5f * tr[t + 256] + 0.5f * lr[t + 256];
  float ss = v0 * v0 + v1 * v1;
#pragma unroll
  for (int o = 32; o > 0; o >>= 1) ss += __shfl_down(ss, o);
  int lane = t & 63, wv = t >> 6;
  if (lane == 0) red[wv] = ss;
  __syncthreads();
  float tot = red[0] + red[1] + red[2] + red[3];
  float scl = rsqrtf(tot * (1.0f / TSD) + 1e-6f);
  float n0 = v0 * scl * wn[t];
  float n1 = v1 * scl * wn[t + 256];
  sv[t] = n0; sv[t + 256] = n1;
  __syncthreads();
  for (int k = 2; k <= TSD; k <<= 1) {
    for (int j = k >> 1; j > 0; j >>= 1) {
#pragma unroll
      for (int u = 0; u < 2; u++) {
        int idx = t + u * 256;
        int ixj = idx ^ j;
        if (ixj > idx) {
          float a = sv[idx], b = sv[ixj];
          bool up = ((idx & k) == 0);
          if ((a > b) == up) { sv[idx] = b; sv[ixj] = a; }
        }
      }
      __syncthreads();
    }
  }
  float kth = sv[KIDX];
  tsf[(size_t)row * TSD + t]       = (bf16_t)fmaxf(n0 - kth, 0.0f);
  tsf[(size_t)row * TSD + t + 256] = (bf16_t)fmaxf(n1 - kth, 0.0f);
}

// ---------------- RoPE in place on [B*NH, S, HD] bf16 ----------------
__global__ void k_rope(bf16_t* __restrict__ x) {
  int gid = blockIdx.x * 256 + threadIdx.x;
  int d = gid & 63;
  int rowi = gid >> 6;
  int s = rowi & (S_LEN - 1);
  bf16_t* p = x + (size_t)rowi * HD;
  float inv = powf(10000.0f, (float)(-2 * d) * (1.0f / 128.0f));
  float ang = (float)s * inv;
  float sn, c;
  sincosf(ang, &sn, &c);
  float x0 = (float)p[d], x1 = (float)p[d + 64];
  p[d]      = (bf16_t)(x0 * c - x1 * sn);
  p[d + 64] = (bf16_t)(x1 * c + x0 * sn);
}

// ---------------- flash attention v3 (causal) ----------------
// Q-tile 128 (wave owns 32 rows), K-tile 64. V pre-transposed [bh][d][s].
// XCD-aware bid mapping: all 16 q-tiles of a head land on one XCD (bid%8),
// so K/V is fetched into that XCD's L2 once and reused 16x.
// Register-prefetch pipeline: next tile's K/V loaded into VGPRs during
// compute of current tile (plain loads don't drain at s_barrier).
__global__ __launch_bounds__(256, 2)
void k_attn(const bf16_t* __restrict__ qb, const bf16_t* __restrict__ kb,
            const bf16_t* __restrict__ vtb, bf16_t* __restrict__ attnB)
{
  __shared__ __align__(16) bf16_t Kt[64 * 128];   // [key][d], swizzled granules
  __shared__ __align__(16) bf16_t Vt[128 * 64];   // [d][key], swizzled granules
  __shared__ __align__(16) bf16_t Pt[128 * 72];   // [qrow][key], stride 72

  const int bid = blockIdx.x;
  const int bh  = (bid & 7) + 8 * (bid >> 7);     // same head -> same XCD (bid%8)
  static const int qmap[16] = {15,0,14,1,13,2,12,3,11,4,10,5,9,6,8,7};
  const int q0 = qmap[((bid >> 3) + (bid >> 8)) & 15] * 128;

  const int tid = threadIdx.x;
  const int lane = tid & 63, w = tid >> 6;
  const int quad = lane >> 4, l15 = lane & 15;

  const bf16_t* Q  = qb  + (size_t)bh * S_LEN * HD;
  const bf16_t* Kg = kb  + (size_t)bh * S_LEN * HD;
  const bf16_t* Vg = vtb + (size_t)bh * HD * S_LEN;   // [d][s]

  // Q fragments: wave w owns rows q0 + w*32 .. +31 (2 sub-tiles of 16)
  bf16x8 qf[2][4];
#pragma unroll
  for (int mi = 0; mi < 2; mi++) {
    const bf16_t* qrow = Q + (size_t)(q0 + w * 32 + mi * 16 + l15) * HD;
#pragma unroll
    for (int c = 0; c < 4; c++)
      qf[mi][c] = *(const bf16x8a*)(qrow + c * 32 + quad * 8);
  }

  // fragment base pointers (swizzle folded in)
  const bf16_t* kfp[4];
#pragma unroll
  for (int c = 0; c < 4; c++)
    kfp[c] = Kt + l15 * 128 + (((c * 4 + quad) ^ (l15 & 7)) * 8);
  const bf16_t* vfp[2];
#pragma unroll
  for (int kc = 0; kc < 2; kc++)
    vfp[kc] = Vt + l15 * 64 + (((kc * 4 + quad) ^ (l15 & 7)) * 8);

  // staging lane constants
  const int vD  = w * 32 + (lane >> 3);
  const int vCc = ((lane & 7) ^ ((lane >> 3) & 7)) * 8;

  f32x4 o[2][8];
#pragma unroll
  for (int mi = 0; mi < 2; mi++)
#pragma unroll
    for (int t8 = 0; t8 < 8; t8++) { f32x4 z = {0.f,0.f,0.f,0.f}; o[mi][t8] = z; }
  float m_i[2][4], l_i[2][4];
#pragma unroll
  for (int mi = 0; mi < 2; mi++)
#pragma unroll
    for (int r = 0; r < 4; r++) { m_i[mi][r] = -1e30f; l_i[mi][r] = 0.0f; }

  const float scale = 0.08838834764831845f;   // 1/sqrt(128)
  const int kEnd = q0 + 64;

  // ---- register prefetch: load K/V tile k0l into kr/vr ----
  bf16x8 kr[4], vr[4];
#pragma unroll
  for (int t = 0; t < 4; t++) {
    kr[t] = *(const bf16x8a*)(Kg + (size_t)(0 + w * 16 + t * 4 + quad) * HD
                              + (l15 ^ ((t * 4 + quad) & 7)) * 8);
    vr[t] = *(const bf16x8a*)(Vg + (size_t)(vD + t * 8) * S_LEN + 0 + vCc);
  }

  for (int k0 = 0; k0 <= kEnd; k0 += 64) {
    const int k0n = (k0 + 64 <= kEnd) ? (k0 + 64) : k0;   // tail: benign refetch
    __syncthreads();    // all waves done reading Kt/Vt from previous step
    // store current tile registers -> LDS
#pragma unroll
    for (int t = 0; t < 4; t++) {
      *(bf16x8a*)(Kt + w * 2048 + t * 512 + lane * 8) = kr[t];
      *(bf16x8a*)(Vt + w * 2048 + t * 512 + lane * 8) = vr[t];
    }
    // issue next tile's loads (in flight across the whole compute phase)
    bf16x8 kn[4], vn[4];
#pragma unroll
    for (int t = 0; t < 4; t++) {
      kn[t] = *(const bf16x8a*)(Kg + (size_t)(k0n + w * 16 + t * 4 + quad) * HD
                                + (l15 ^ ((t * 4 + quad) & 7)) * 8);
      vn[t] = *(const bf16x8a*)(Vg + (size_t)(vD + t * 8) * S_LEN + k0n + vCc);
    }
    __syncthreads();    // Kt/Vt ready

    // S = Q K^T
    f32x4 st[2][4];
#pragma unroll
    for (int mi = 0; mi < 2; mi++)
#pragma unroll
      for (int nt = 0; nt < 4; nt++) { f32x4 z = {0.f,0.f,0.f,0.f}; st[mi][nt] = z; }
#pragma unroll
    for (int nt = 0; nt < 4; nt++)
#pragma unroll
      for (int c = 0; c < 4; c++) {
        bf16x8 kf = *(const bf16x8a*)(kfp[c] + nt * 2048);
        st[0][nt] = mfma_bf16(qf[0][c], kf, st[0][nt]);
        st[1][nt] = mfma_bf16(qf[1][c], kf, st[1][nt]);
      }

    // scale + causal mask + online softmax (per 16-row sub-tile)
    float alpha[2][4];
#pragma unroll
    for (int mi = 0; mi < 2; mi++) {
      const int rowBase = q0 + w * 32 + mi * 16;
      const bool tileMask = (k0 + 63) > rowBase;
#pragma unroll
      for (int nt = 0; nt < 4; nt++)
#pragma unroll
        for (int r = 0; r < 4; r++) {
          float v = st[mi][nt][r] * scale;
          if (tileMask) {
            int row = rowBase + quad * 4 + r;
            int col = k0 + nt * 16 + l15;
            if (col > row) v = -1e9f;
          }
          st[mi][nt][r] = v;
        }
#pragma unroll
      for (int r = 0; r < 4; r++) {
        float mx = fmaxf(fmaxf(st[mi][0][r], st[mi][1][r]),
                         fmaxf(st[mi][2][r], st[mi][3][r]));
#pragma unroll
        for (int off = 1; off < 16; off <<= 1)
          mx = fmaxf(mx, __shfl_xor(mx, off, 16));
        float mnew = fmaxf(m_i[mi][r], mx);
        alpha[mi][r] = __expf(m_i[mi][r] - mnew);
        m_i[mi][r] = mnew;
        float rowsum = 0.0f;
#pragma unroll
        for (int nt = 0; nt < 4; nt++) {
          float pv = __expf(st[mi][nt][r] - mnew);
          pv = (float)(bf16_t)pv;
          st[mi][nt][r] = pv;
          rowsum += pv;
        }
#pragma unroll
        for (int off = 1; off < 16; off <<= 1)
          rowsum += __shfl_xor(rowsum, off, 16);
        l_i[mi][r] = l_i[mi][r] * alpha[mi][r] + rowsum;
      }
    }

    // write P (per-wave private rows w*32..+31)
#pragma unroll
    for (int mi = 0; mi < 2; mi++)
#pragma unroll
      for (int nt = 0; nt < 4; nt++)
#pragma unroll
        for (int r = 0; r < 4; r++)
          Pt[(w * 32 + mi * 16 + quad * 4 + r) * 72 + nt * 16 + l15] =
              (bf16_t)st[mi][nt][r];

    // rescale O
#pragma unroll
    for (int mi = 0; mi < 2; mi++)
#pragma unroll
      for (int t8 = 0; t8 < 8; t8++)
#pragma unroll
        for (int r = 0; r < 4; r++)
          o[mi][t8][r] *= alpha[mi][r];

    // O += P * V
#pragma unroll
    for (int kc = 0; kc < 2; kc++) {
      bf16x8 pf0 = *(const bf16x8a*)(Pt + (w * 32 +      l15) * 72 + kc * 32 + quad * 8);
      bf16x8 pf1 = *(const bf16x8a*)(Pt + (w * 32 + 16 + l15) * 72 + kc * 32 + quad * 8);
#pragma unroll
      for (int t8 = 0; t8 < 8; t8++) {
        bf16x8 vf = *(const bf16x8a*)(vfp[kc] + t8 * 1024);
        o[0][t8] = mfma_bf16(pf0, vf, o[0][t8]);
        o[1][t8] = mfma_bf16(pf1, vf, o[1][t8]);
      }
    }

    // roll prefetched registers
#pragma unroll
    for (int t = 0; t < 4; t++) { kr[t] = kn[t]; vr[t] = vn[t]; }
  }

  const int b = bh >> 4, h = bh & 15;
#pragma unroll
  for (int mi = 0; mi < 2; mi++)
#pragma unroll
    for (int r = 0; r < 4; r++) {
      float rl = 1.0f / l_i[mi][r];
      int qr = q0 + w * 32 + mi * 16 + quad * 4 + r;
#pragma unroll
      for (int t8 = 0; t8 < 8; t8++) {
        int col = h * HD + t8 * 16 + l15;
        attnB[(size_t)(b * S_LEN + qr) * HDIM + col] = (bf16_t)(o[mi][t8][r] * rl);
      }
    }
}

// ---------------- launcher ----------------
extern "C" void kernel_launch(void* const* d_in, const int* in_sizes, int n_in,
                              void* d_out, int out_size, void* d_ws, size_t ws_size,
                              hipStream_t stream) {
  const float* hs    = (const float*)d_in[0];
  const float* lte   = (const float*)d_in[1];
  const float* Wq    = (const float*)d_in[2];
  const float* Wk    = (const float*)d_in[3];
  const float* Wv    = (const float*)d_in[4];
  const float* Wo    = (const float*)d_in[5];
  const float* Wts   = (const float*)d_in[6];
  const float* tsw   = (const float*)d_in[7];
  const float* Worig = (const float*)d_in[8];
  float* out = (float*)d_out;

  char* p = (char*)d_ws;
  bf16_t* hsB   = (bf16_t*)(p);                    // 16 MB [4096][2048]
  bf16_t* wT    = (bf16_t*)(p + 16777216);         //  8 MB reused per GEMM
  float*  tsB   = (float*)(p + 25165824);          //  8 MB [4096][512]
  bf16_t* tsf   = (bf16_t*)(p + 33554432);         //  4 MB [4096][512]
  bf16_t* qkadd = (bf16_t*)(p + 37748736);         // 32 MB [4096][4096] (dead after QKV)
  bf16_t* attnB = qkadd;                           // 16 MB alias (lower half)
  bf16_t* vtb   = (bf16_t*)(p + 54525952);         // 16 MB alias (upper half) [bh][d][s]
  bf16_t* qbuf  = (bf16_t*)(p + 71303168);         // 16 MB [32][2048][128]
  bf16_t* kbuf  = (bf16_t*)(p + 88080384);         // 16 MB
  bf16_t* vbuf  = (bf16_t*)(p + 104857600);        // 16 MB -> total 121,634,816

  k_cvt<<<8192, 256, 0, stream>>>(hs, hsB, BROWS * HDIM);
  k_transpose<<<dim3(16, 64), dim3(32, 8), 0, stream>>>(Wts, wT, 2048, 512, 512);
  k_gemm<0><<<dim3(4, 32), 256, 0, stream>>>(hsB, wT, tsB, nullptr, nullptr,
                                             4096, 512, 2048, 0, 0);
  k_tsproc<<<4096, 256, 0, stream>>>(tsB, lte, tsw, tsf);
  k_transpose<<<dim3(128, 16), dim3(32, 8), 0, stream>>>(Worig, wT, 512, 4096, 6144);
  k_gemm<1><<<dim3(32, 32), 256, 0, stream>>>(tsf, wT, nullptr, qkadd, nullptr,
                                              4096, 4096, 512, 0, 0);
  k_transpose<<<dim3(64, 64), dim3(32, 8), 0, stream>>>(Wq, wT, 2048, 2048, 2048);
  k_gemm<2><<<dim3(16, 32), 256, 0, stream>>>(hsB, wT, nullptr, qbuf, qkadd,
                                              4096, 2048, 2048, 4096, 0);
  k_transpose<<<dim3(64, 64), dim3(32, 8), 0, stream>>>(Wk, wT, 2048, 2048, 2048);
  k_gemm<2><<<dim3(16, 32), 256, 0, stream>>>(hsB, wT, nullptr, kbuf, qkadd,
                                              4096, 2048, 2048, 4096, 2048);
  k_transpose<<<dim3(64, 64), dim3(32, 8), 0, stream>>>(Wv, wT, 2048, 2048, 2048);
  k_gemm<2><<<dim3(16, 32), 256, 0, stream>>>(hsB, wT, nullptr, vbuf, qkadd,
                                              4096, 2048, 2048, 4096, 2048);
  k_rope<<<16384, 256, 0, stream>>>(qbuf);
  k_rope<<<16384, 256, 0, stream>>>(kbuf);
  k_vtrans<<<dim3(32, 2, 32), 256, 0, stream>>>(vbuf, vtb);
  k_transpose<<<dim3(64, 64), dim3(32, 8), 0, stream>>>(Wo, wT, 2048, 2048, 2048);
  k_attn<<<512, 256, 0, stream>>>(qbuf, kbuf, vtb, attnB);
  k_gemm<0><<<dim3(16, 32), 256, 0, stream>>>(attnB, wT, out, nullptr, nullptr,
                                              4096, 2048, 2048, 0, 0);
}

// Round 4
// 682.546 us; speedup vs baseline: 1.2218x; 1.0534x over previous
//
#include <hip/hip_runtime.h>
#include <cstdint>

// ---------------- types ----------------
typedef __bf16 bf16_t;
typedef __bf16 bf16x8 __attribute__((ext_vector_type(8)));
typedef __bf16 bf16x4 __attribute__((ext_vector_type(4)));
typedef float  f32x4  __attribute__((ext_vector_type(4)));
typedef bf16x8 __attribute__((may_alias)) bf16x8a;
typedef bf16x4 __attribute__((may_alias)) bf16x4a;
typedef f32x4  __attribute__((may_alias)) f32x4a;

#define S_LEN 2048
#define HDIM  2048
#define NHEAD 16
#define HD    128
#define TSD   512
#define BROWS 4096   // B * S
#define KIDX  459    // K_IDX - 1

__device__ __forceinline__ f32x4 mfma_bf16(bf16x8 a, bf16x8 b, f32x4 c) {
  return __builtin_amdgcn_mfma_f32_16x16x32_bf16(a, b, c, 0, 0, 0);
}

__device__ __forceinline__ void gld_lds16(const bf16_t* g, bf16_t* l) {
  __builtin_amdgcn_global_load_lds(
      (__attribute__((address_space(1))) void*)(void*)const_cast<bf16_t*>(g),
      (__attribute__((address_space(3))) void*)(void*)(l), 16, 0, 0);
}

// ---------------- elementwise convert fp32 -> bf16 ----------------
__global__ void k_cvt(const float* __restrict__ in, bf16_t* __restrict__ out, int n) {
  int i = (blockIdx.x * 256 + threadIdx.x) * 4;
  if (i >= n) return;
  f32x4 v = *(const f32x4a*)(in + i);
  bf16x4 o = { (bf16_t)v.x, (bf16_t)v.y, (bf16_t)v.z, (bf16_t)v.w };
  *(bf16x4a*)(out + i) = o;
}

// ---------------- transpose + convert: out[c][r] = in[r][c] ----------------
__global__ void k_transpose(const float* __restrict__ in, bf16_t* __restrict__ out,
                            int R, int C, int ldin) {
  __shared__ float tile[32][33];
  int c0 = blockIdx.x * 32, r0 = blockIdx.y * 32;
  int tx = threadIdx.x, ty = threadIdx.y;
  for (int i = ty; i < 32; i += 8)
    tile[i][tx] = in[(size_t)(r0 + i) * ldin + c0 + tx];
  __syncthreads();
  for (int i = ty; i < 32; i += 8)
    out[(size_t)(c0 + i) * R + r0 + tx] = (bf16_t)tile[tx][i];
}

// ---------------- bf16 transpose: vbuf [bh][s][d] -> vtb [bh][d][s] ----------------
__global__ void k_vtrans(const bf16_t* __restrict__ in, bf16_t* __restrict__ out) {
  __shared__ bf16_t t[64][72];
  int s0 = blockIdx.x * 64, d0 = blockIdx.y * 64, bh = blockIdx.z;
  const bf16_t* src = in + (size_t)bh * S_LEN * HD;
  bf16_t* dst = out + (size_t)bh * HD * S_LEN;
  int tid = threadIdx.x;
  for (int g = tid; g < 512; g += 256) {
    int r = g >> 3, cc = g & 7;
    *(bf16x8a*)&t[r][cc * 8] = *(const bf16x8a*)(src + (size_t)(s0 + r) * HD + d0 + cc * 8);
  }
  __syncthreads();
  for (int g = tid; g < 512; g += 256) {
    int dr = g >> 3, sc = g & 7;
    bf16x8 v;
#pragma unroll
    for (int j = 0; j < 8; j++) v[j] = t[sc * 8 + j][dr];
    *(bf16x8a*)(dst + (size_t)(d0 + dr) * S_LEN + s0 + sc * 8) = v;
  }
}

// ---------------- bf16 MFMA GEMM, B pre-transposed (N x K) ----------------
template<int MODE>
__global__ __launch_bounds__(256)
void k_gemm(const bf16_t* __restrict__ A, const bf16_t* __restrict__ Bt,
            float* __restrict__ outF, bf16_t* __restrict__ outB,
            const bf16_t* __restrict__ addend, int M, int N, int K,
            int addLd, int addCol)
{
  __shared__ __align__(16) bf16_t As[128 * 32];
  __shared__ __align__(16) bf16_t Bs[128 * 32];
  const int tid  = threadIdx.x;
  const int lane = tid & 63, w = tid >> 6;
  const int quad = lane >> 4, l15 = lane & 15;
  const int m0 = blockIdx.y * 128, n0 = blockIdx.x * 128;
  const int wm = (w >> 1) * 64, wn = (w & 1) * 64;

  f32x4 acc[4][4];
#pragma unroll
  for (int i = 0; i < 4; i++)
#pragma unroll
    for (int j = 0; j < 4; j++) { f32x4 z = {0.f,0.f,0.f,0.f}; acc[i][j] = z; }

  const int srow = w * 16 + (lane >> 2);
  const int scol = (lane & 3) * 8;

  for (int k0 = 0; k0 < K; k0 += 32) {
    __syncthreads();
    gld_lds16(A  + (size_t)(m0 +      srow) * K + k0 + scol, As + (size_t)w * 512);
    gld_lds16(A  + (size_t)(m0 + 64 + srow) * K + k0 + scol, As + (size_t)(4 + w) * 512);
    gld_lds16(Bt + (size_t)(n0 +      srow) * K + k0 + scol, Bs + (size_t)w * 512);
    gld_lds16(Bt + (size_t)(n0 + 64 + srow) * K + k0 + scol, Bs + (size_t)(4 + w) * 512);
    __syncthreads();
    bf16x8 af[4], bv[4];
#pragma unroll
    for (int i = 0; i < 4; i++)
      af[i] = *(const bf16x8a*)&As[(wm + i * 16 + l15) * 32 + quad * 8];
#pragma unroll
    for (int j = 0; j < 4; j++)
      bv[j] = *(const bf16x8a*)&Bs[(wn + j * 16 + l15) * 32 + quad * 8];
#pragma unroll
    for (int i = 0; i < 4; i++)
#pragma unroll
      for (int j = 0; j < 4; j++)
        acc[i][j] = mfma_bf16(af[i], bv[j], acc[i][j]);
  }

#pragma unroll
  for (int i = 0; i < 4; i++)
#pragma unroll
    for (int j = 0; j < 4; j++)
#pragma unroll
      for (int r = 0; r < 4; r++) {
        int row = m0 + wm + i * 16 + quad * 4 + r;
        int col = n0 + wn + j * 16 + l15;
        float v = acc[i][j][r];
        if (MODE == 0) {
          outF[(size_t)row * N + col] = v;
        } else if (MODE == 1) {
          outB[(size_t)row * N + col] = (bf16_t)v;
        } else {
          v += (float)addend[(size_t)row * addLd + addCol + col];
          int s = row & (S_LEN - 1), b = row >> 11;
          int h = col >> 7, d = col & (HD - 1);
          outB[(((size_t)(b * NHEAD + h) * S_LEN) + s) * HD + d] = (bf16_t)v;
        }
      }
}

// ---------------- blend + rmsnorm + kth-threshold + relu ----------------
__global__ __launch_bounds__(256)
void k_tsproc(const float* __restrict__ ts, const float* __restrict__ lte,
              const float* __restrict__ wn, bf16_t* __restrict__ tsf)
{
  __shared__ float sv[TSD];
  __shared__ float red[4];
  int row = blockIdx.x;
  int t = threadIdx.x;
  const float* tr = ts  + (size_t)row * TSD;
  const float* lr = lte + (size_t)row * TSD;
  float v0 = 0.5f * tr[t] + 0.5f * lr[t];
  float v1 = 0.5f * tr[t + 256] + 0.5f * lr[t + 256];
  float ss = v0 * v0 + v1 * v1;
#pragma unroll
  for (int o = 32; o > 0; o >>= 1) ss += __shfl_down(ss, o);
  int lane = t & 63, wv = t >> 6;
  if (lane == 0) red[wv] = ss;
  __syncthreads();
  float tot = red[0] + red[1] + red[2] + red[3];
  float scl = rsqrtf(tot * (1.0f / TSD) + 1e-6f);
  float n0 = v0 * scl * wn[t];
  float n1 = v1 * scl * wn[t + 256];
  sv[t] = n0; sv[t + 256] = n1;
  __syncthreads();
  for (int k = 2; k <= TSD; k <<= 1) {
    for (int j = k >> 1; j > 0; j >>= 1) {
#pragma unroll
      for (int u = 0; u < 2; u++) {
        int idx = t + u * 256;
        int ixj = idx ^ j;
        if (ixj > idx) {
          float a = sv[idx], b = sv[ixj];
          bool up = ((idx & k) == 0);
          if ((a > b) == up) { sv[idx] = b; sv[ixj] = a; }
        }
      }
      __syncthreads();
    }
  }
  float kth = sv[KIDX];
  tsf[(size_t)row * TSD + t]       = (bf16_t)fmaxf(n0 - kth, 0.0f);
  tsf[(size_t)row * TSD + t + 256] = (bf16_t)fmaxf(n1 - kth, 0.0f);
}

// ---------------- RoPE in place on [B*NH, S, HD] bf16 ----------------
__global__ void k_rope(bf16_t* __restrict__ x) {
  int gid = blockIdx.x * 256 + threadIdx.x;
  int d = gid & 63;
  int rowi = gid >> 6;
  int s = rowi & (S_LEN - 1);
  bf16_t* p = x + (size_t)rowi * HD;
  float inv = powf(10000.0f, (float)(-2 * d) * (1.0f / 128.0f));
  float ang = (float)s * inv;
  float sn, c;
  sincosf(ang, &sn, &c);
  float x0 = (float)p[d], x1 = (float)p[d + 64];
  p[d]      = (bf16_t)(x0 * c - x1 * sn);
  p[d + 64] = (bf16_t)(x1 * c + x0 * sn);
}

// ---------------- flash attention v4 (causal) ----------------
// Q-tile 128, K-tile 64, 8 waves x 16 q-rows (512 threads) -> 16 waves/CU.
// V pre-transposed [bh][d][s]. XCD-aware bid mapping (head -> one XCD's L2).
// Register-prefetch pipeline for next K/V tile; XOR-swizzled LDS granules.
__global__ __launch_bounds__(512, 4)
void k_attn(const bf16_t* __restrict__ qb, const bf16_t* __restrict__ kb,
            const bf16_t* __restrict__ vtb, bf16_t* __restrict__ attnB)
{
  __shared__ __align__(16) bf16_t Kt[64 * 128];   // [key][d], swizzled granules
  __shared__ __align__(16) bf16_t Vt[128 * 64];   // [d][key], swizzled granules
  __shared__ __align__(16) bf16_t Pt[128 * 72];   // [qrow][key], stride 72

  const int bid = blockIdx.x;
  const int bh  = (bid & 7) + 8 * (bid >> 7);     // same head -> same XCD (bid%8)
  static const int qmap[16] = {15,0,14,1,13,2,12,3,11,4,10,5,9,6,8,7};
  const int q0 = qmap[((bid >> 3) + (bid >> 8)) & 15] * 128;

  const int tid = threadIdx.x;
  const int lane = tid & 63, w = tid >> 6;        // 8 waves
  const int quad = lane >> 4, l15 = lane & 15;

  const bf16_t* Q  = qb  + (size_t)bh * S_LEN * HD;
  const bf16_t* Kg = kb  + (size_t)bh * S_LEN * HD;
  const bf16_t* Vg = vtb + (size_t)bh * HD * S_LEN;   // [d][s]

  // Q fragments: wave w owns rows q0 + w*16 .. +15
  bf16x8 qf[4];
  {
    const bf16_t* qrow = Q + (size_t)(q0 + w * 16 + l15) * HD;
#pragma unroll
    for (int c = 0; c < 4; c++)
      qf[c] = *(const bf16x8a*)(qrow + c * 32 + quad * 8);
  }

  // fragment base pointers (swizzle folded in)
  const bf16_t* kfp[4];
#pragma unroll
  for (int c = 0; c < 4; c++)
    kfp[c] = Kt + l15 * 128 + (((c * 4 + quad) ^ (l15 & 7)) * 8);
  const bf16_t* vfp[2];
#pragma unroll
  for (int kc = 0; kc < 2; kc++)
    vfp[kc] = Vt + l15 * 64 + (((kc * 4 + quad) ^ (l15 & 7)) * 8);

  // staging thread constants (512 threads, 2 granules each for K and V)
  const int kR   = tid >> 4;                     // K granule 0: row 0..31
  const int kCg  = tid & 15;
  const size_t kG = (size_t)kR * HD + kCg * 8;   // + 32*HD for granule 1
  const int kL   = kR * 128 + ((kCg ^ (kR & 7)) * 8);   // + 4096 for granule 1
  const int vD0  = tid >> 3;                     // V granule 0: d 0..63
  const int vKg  = tid & 7;
  const size_t vG = (size_t)vD0 * S_LEN + vKg * 8;      // + 64*S_LEN for granule 1
  const int vL   = vD0 * 64 + ((vKg ^ (vD0 & 7)) * 8);  // + 4096 for granule 1

  f32x4 o[8];
#pragma unroll
  for (int t8 = 0; t8 < 8; t8++) { f32x4 z = {0.f,0.f,0.f,0.f}; o[t8] = z; }
  float m_i[4], l_i[4];
#pragma unroll
  for (int r = 0; r < 4; r++) { m_i[r] = -1e30f; l_i[r] = 0.0f; }

  const float scale = 0.08838834764831845f;   // 1/sqrt(128)
  const int kEnd = q0 + 64;

  // ---- register prefetch: tile k0=0 ----
  bf16x8 kr[2], vr[2];
  kr[0] = *(const bf16x8a*)(Kg + kG);
  kr[1] = *(const bf16x8a*)(Kg + kG + (size_t)32 * HD);
  vr[0] = *(const bf16x8a*)(Vg + vG);
  vr[1] = *(const bf16x8a*)(Vg + vG + (size_t)64 * S_LEN);

  for (int k0 = 0; k0 <= kEnd; k0 += 64) {
    const int k0n = (k0 + 64 <= kEnd) ? (k0 + 64) : k0;   // tail: benign refetch
    __syncthreads();    // all waves done reading Kt/Vt from previous step
    // store current tile registers -> LDS
    *(bf16x8a*)(Kt + kL)        = kr[0];
    *(bf16x8a*)(Kt + kL + 4096) = kr[1];
    *(bf16x8a*)(Vt + vL)        = vr[0];
    *(bf16x8a*)(Vt + vL + 4096) = vr[1];
    // issue next tile's loads (in flight across the whole compute phase)
    bf16x8 kn[2], vn[2];
    kn[0] = *(const bf16x8a*)(Kg + (size_t)k0n * HD + kG);
    kn[1] = *(const bf16x8a*)(Kg + (size_t)k0n * HD + kG + (size_t)32 * HD);
    vn[0] = *(const bf16x8a*)(Vg + vG + k0n);
    vn[1] = *(const bf16x8a*)(Vg + vG + k0n + (size_t)64 * S_LEN);
    __syncthreads();    // Kt/Vt ready

    // S = Q K^T
    f32x4 st[4];
#pragma unroll
    for (int nt = 0; nt < 4; nt++) { f32x4 z = {0.f,0.f,0.f,0.f}; st[nt] = z; }
#pragma unroll
    for (int nt = 0; nt < 4; nt++)
#pragma unroll
      for (int c = 0; c < 4; c++) {
        bf16x8 kf = *(const bf16x8a*)(kfp[c] + nt * 2048);
        st[nt] = mfma_bf16(qf[c], kf, st[nt]);
      }

    // scale + causal mask + online softmax (16 rows per wave)
    const int rowBase = q0 + w * 16;
    const bool tileMask = (k0 + 63) > rowBase;
    float alpha[4];
#pragma unroll
    for (int nt = 0; nt < 4; nt++)
#pragma unroll
      for (int r = 0; r < 4; r++) {
        float v = st[nt][r] * scale;
        if (tileMask) {
          int row = rowBase + quad * 4 + r;
          int col = k0 + nt * 16 + l15;
          if (col > row) v = -1e9f;
        }
        st[nt][r] = v;
      }
#pragma unroll
    for (int r = 0; r < 4; r++) {
      float mx = fmaxf(fmaxf(st[0][r], st[1][r]), fmaxf(st[2][r], st[3][r]));
#pragma unroll
      for (int off = 1; off < 16; off <<= 1)
        mx = fmaxf(mx, __shfl_xor(mx, off, 16));
      float mnew = fmaxf(m_i[r], mx);
      alpha[r] = __expf(m_i[r] - mnew);
      m_i[r] = mnew;
      float rowsum = 0.0f;
#pragma unroll
      for (int nt = 0; nt < 4; nt++) {
        float pv = __expf(st[nt][r] - mnew);
        pv = (float)(bf16_t)pv;
        st[nt][r] = pv;
        rowsum += pv;
      }
#pragma unroll
      for (int off = 1; off < 16; off <<= 1)
        rowsum += __shfl_xor(rowsum, off, 16);
      l_i[r] = l_i[r] * alpha[r] + rowsum;
    }

    // write P (per-wave private rows w*16..+15)
#pragma unroll
    for (int nt = 0; nt < 4; nt++)
#pragma unroll
      for (int r = 0; r < 4; r++)
        Pt[(w * 16 + quad * 4 + r) * 72 + nt * 16 + l15] = (bf16_t)st[nt][r];

    // rescale O
#pragma unroll
    for (int t8 = 0; t8 < 8; t8++)
#pragma unroll
      for (int r = 0; r < 4; r++)
        o[t8][r] *= alpha[r];

    // O += P * V
#pragma unroll
    for (int kc = 0; kc < 2; kc++) {
      bf16x8 pf = *(const bf16x8a*)(Pt + (w * 16 + l15) * 72 + kc * 32 + quad * 8);
#pragma unroll
      for (int t8 = 0; t8 < 8; t8++) {
        bf16x8 vf = *(const bf16x8a*)(vfp[kc] + t8 * 1024);
        o[t8] = mfma_bf16(pf, vf, o[t8]);
      }
    }

    // roll prefetched registers
    kr[0] = kn[0]; kr[1] = kn[1]; vr[0] = vn[0]; vr[1] = vn[1];
  }

  const int b = bh >> 4, h = bh & 15;
#pragma unroll
  for (int r = 0; r < 4; r++) {
    float rl = 1.0f / l_i[r];
    int qr = q0 + w * 16 + quad * 4 + r;
#pragma unroll
    for (int t8 = 0; t8 < 8; t8++) {
      int col = h * HD + t8 * 16 + l15;
      attnB[(size_t)(b * S_LEN + qr) * HDIM + col] = (bf16_t)(o[t8][r] * rl);
    }
  }
}

// ---------------- launcher ----------------
extern "C" void kernel_launch(void* const* d_in, const int* in_sizes, int n_in,
                              void* d_out, int out_size, void* d_ws, size_t ws_size,
                              hipStream_t stream) {
  const float* hs    = (const float*)d_in[0];
  const float* lte   = (const float*)d_in[1];
  const float* Wq    = (const float*)d_in[2];
  const float* Wk    = (const float*)d_in[3];
  const float* Wv    = (const float*)d_in[4];
  const float* Wo    = (const float*)d_in[5];
  const float* Wts   = (const float*)d_in[6];
  const float* tsw   = (const float*)d_in[7];
  const float* Worig = (const float*)d_in[8];
  float* out = (float*)d_out;

  char* p = (char*)d_ws;
  bf16_t* hsB   = (bf16_t*)(p);                    // 16 MB [4096][2048]
  bf16_t* wT    = (bf16_t*)(p + 16777216);         //  8 MB reused per GEMM
  float*  tsB   = (float*)(p + 25165824);          //  8 MB [4096][512]
  bf16_t* tsf   = (bf16_t*)(p + 33554432);         //  4 MB [4096][512]
  bf16_t* qkadd = (bf16_t*)(p + 37748736);         // 32 MB [4096][4096] (dead after QKV)
  bf16_t* attnB = qkadd;                           // 16 MB alias (lower half)
  bf16_t* vtb   = (bf16_t*)(p + 54525952);         // 16 MB alias (upper half) [bh][d][s]
  bf16_t* qbuf  = (bf16_t*)(p + 71303168);         // 16 MB [32][2048][128]
  bf16_t* kbuf  = (bf16_t*)(p + 88080384);         // 16 MB
  bf16_t* vbuf  = (bf16_t*)(p + 104857600);        // 16 MB -> total 121,634,816

  k_cvt<<<8192, 256, 0, stream>>>(hs, hsB, BROWS * HDIM);
  k_transpose<<<dim3(16, 64), dim3(32, 8), 0, stream>>>(Wts, wT, 2048, 512, 512);
  k_gemm<0><<<dim3(4, 32), 256, 0, stream>>>(hsB, wT, tsB, nullptr, nullptr,
                                             4096, 512, 2048, 0, 0);
  k_tsproc<<<4096, 256, 0, stream>>>(tsB, lte, tsw, tsf);
  k_transpose<<<dim3(128, 16), dim3(32, 8), 0, stream>>>(Worig, wT, 512, 4096, 6144);
  k_gemm<1><<<dim3(32, 32), 256, 0, stream>>>(tsf, wT, nullptr, qkadd, nullptr,
                                              4096, 4096, 512, 0, 0);
  k_transpose<<<dim3(64, 64), dim3(32, 8), 0, stream>>>(Wq, wT, 2048, 2048, 2048);
  k_gemm<2><<<dim3(16, 32), 256, 0, stream>>>(hsB, wT, nullptr, qbuf, qkadd,
                                              4096, 2048, 2048, 4096, 0);
  k_transpose<<<dim3(64, 64), dim3(32, 8), 0, stream>>>(Wk, wT, 2048, 2048, 2048);
  k_gemm<2><<<dim3(16, 32), 256, 0, stream>>>(hsB, wT, nullptr, kbuf, qkadd,
                                              4096, 2048, 2048, 4096, 2048);
  k_transpose<<<dim3(64, 64), dim3(32, 8), 0, stream>>>(Wv, wT, 2048, 2048, 2048);
  k_gemm<2><<<dim3(16, 32), 256, 0, stream>>>(hsB, wT, nullptr, vbuf, qkadd,
                                              4096, 2048, 2048, 4096, 2048);
  k_rope<<<16384, 256, 0, stream>>>(qbuf);
  k_rope<<<16384, 256, 0, stream>>>(kbuf);
  k_vtrans<<<dim3(32, 2, 32), 256, 0, stream>>>(vbuf, vtb);
  k_transpose<<<dim3(64, 64), dim3(32, 8), 0, stream>>>(Wo, wT, 2048, 2048, 2048);
  k_attn<<<512, 512, 0, stream>>>(qbuf, kbuf, vtb, attnB);
  k_gemm<0><<<dim3(16, 32), 256, 0, stream>>>(attnB, wT, out, nullptr, nullptr,
                                              4096, 2048, 2048, 0, 0);
}

// Round 5
// 634.976 us; speedup vs baseline: 1.3134x; 1.0749x over previous
//
#include <hip/hip_runtime.h>
#include <cstdint>

// ---------------- types ----------------
typedef __bf16 bf16_t;
typedef __bf16 bf16x8 __attribute__((ext_vector_type(8)));
typedef __bf16 bf16x4 __attribute__((ext_vector_type(4)));
typedef float  f32x4  __attribute__((ext_vector_type(4)));
typedef bf16x8 __attribute__((may_alias)) bf16x8a;
typedef bf16x4 __attribute__((may_alias)) bf16x4a;
typedef f32x4  __attribute__((may_alias)) f32x4a;

#define S_LEN 2048
#define HDIM  2048
#define NHEAD 16
#define HD    128
#define TSD   512
#define BROWS 4096   // B * S
#define KIDX  459    // K_IDX - 1

__device__ __forceinline__ f32x4 mfma_bf16(bf16x8 a, bf16x8 b, f32x4 c) {
  return __builtin_amdgcn_mfma_f32_16x16x32_bf16(a, b, c, 0, 0, 0);
}

__device__ __forceinline__ void gld_lds16(const bf16_t* g, bf16_t* l) {
  __builtin_amdgcn_global_load_lds(
      (__attribute__((address_space(1))) void*)(void*)const_cast<bf16_t*>(g),
      (__attribute__((address_space(3))) void*)(void*)(l), 16, 0, 0);
}

__device__ __forceinline__ uint32_t pk2(float a, float b) {
  union { bf16_t h; uint16_t u; } ua, ub;
  ua.h = (bf16_t)a; ub.h = (bf16_t)b;
  return (uint32_t)ua.u | ((uint32_t)ub.u << 16);
}

// ---------------- elementwise convert fp32 -> bf16 ----------------
__global__ void k_cvt(const float* __restrict__ in, bf16_t* __restrict__ out, int n) {
  int i = (blockIdx.x * 256 + threadIdx.x) * 4;
  if (i >= n) return;
  f32x4 v = *(const f32x4a*)(in + i);
  bf16x4 o = { (bf16_t)v.x, (bf16_t)v.y, (bf16_t)v.z, (bf16_t)v.w };
  *(bf16x4a*)(out + i) = o;
}

// ---------------- transpose + convert: out[c][r] = in[r][c] ----------------
__global__ void k_transpose(const float* __restrict__ in, bf16_t* __restrict__ out,
                            int R, int C, int ldin) {
  __shared__ float tile[32][33];
  int c0 = blockIdx.x * 32, r0 = blockIdx.y * 32;
  int tx = threadIdx.x, ty = threadIdx.y;
  for (int i = ty; i < 32; i += 8)
    tile[i][tx] = in[(size_t)(r0 + i) * ldin + c0 + tx];
  __syncthreads();
  for (int i = ty; i < 32; i += 8)
    out[(size_t)(c0 + i) * R + r0 + tx] = (bf16_t)tile[tx][i];
}

// ---------------- bf16 transpose: vbuf [bh][s][d] -> vtb [bh][d][s] ----------------
__global__ void k_vtrans(const bf16_t* __restrict__ in, bf16_t* __restrict__ out) {
  __shared__ bf16_t t[64][72];
  int s0 = blockIdx.x * 64, d0 = blockIdx.y * 64, bh = blockIdx.z;
  const bf16_t* src = in + (size_t)bh * S_LEN * HD;
  bf16_t* dst = out + (size_t)bh * HD * S_LEN;
  int tid = threadIdx.x;
  for (int g = tid; g < 512; g += 256) {
    int r = g >> 3, cc = g & 7;
    *(bf16x8a*)&t[r][cc * 8] = *(const bf16x8a*)(src + (size_t)(s0 + r) * HD + d0 + cc * 8);
  }
  __syncthreads();
  for (int g = tid; g < 512; g += 256) {
    int dr = g >> 3, sc = g & 7;
    bf16x8 v;
#pragma unroll
    for (int j = 0; j < 8; j++) v[j] = t[sc * 8 + j][dr];
    *(bf16x8a*)(dst + (size_t)(d0 + dr) * S_LEN + s0 + sc * 8) = v;
  }
}

// ---------------- bf16 MFMA GEMM, B pre-transposed (N x K) ----------------
template<int MODE>
__global__ __launch_bounds__(256)
void k_gemm(const bf16_t* __restrict__ A, const bf16_t* __restrict__ Bt,
            float* __restrict__ outF, bf16_t* __restrict__ outB,
            const bf16_t* __restrict__ addend, int M, int N, int K,
            int addLd, int addCol)
{
  __shared__ __align__(16) bf16_t As[128 * 32];
  __shared__ __align__(16) bf16_t Bs[128 * 32];
  const int tid  = threadIdx.x;
  const int lane = tid & 63, w = tid >> 6;
  const int quad = lane >> 4, l15 = lane & 15;
  const int m0 = blockIdx.y * 128, n0 = blockIdx.x * 128;
  const int wm = (w >> 1) * 64, wn = (w & 1) * 64;

  f32x4 acc[4][4];
#pragma unroll
  for (int i = 0; i < 4; i++)
#pragma unroll
    for (int j = 0; j < 4; j++) { f32x4 z = {0.f,0.f,0.f,0.f}; acc[i][j] = z; }

  const int srow = w * 16 + (lane >> 2);
  const int scol = (lane & 3) * 8;

  for (int k0 = 0; k0 < K; k0 += 32) {
    __syncthreads();
    gld_lds16(A  + (size_t)(m0 +      srow) * K + k0 + scol, As + (size_t)w * 512);
    gld_lds16(A  + (size_t)(m0 + 64 + srow) * K + k0 + scol, As + (size_t)(4 + w) * 512);
    gld_lds16(Bt + (size_t)(n0 +      srow) * K + k0 + scol, Bs + (size_t)w * 512);
    gld_lds16(Bt + (size_t)(n0 + 64 + srow) * K + k0 + scol, Bs + (size_t)(4 + w) * 512);
    __syncthreads();
    bf16x8 af[4], bv[4];
#pragma unroll
    for (int i = 0; i < 4; i++)
      af[i] = *(const bf16x8a*)&As[(wm + i * 16 + l15) * 32 + quad * 8];
#pragma unroll
    for (int j = 0; j < 4; j++)
      bv[j] = *(const bf16x8a*)&Bs[(wn + j * 16 + l15) * 32 + quad * 8];
#pragma unroll
    for (int i = 0; i < 4; i++)
#pragma unroll
      for (int j = 0; j < 4; j++)
        acc[i][j] = mfma_bf16(af[i], bv[j], acc[i][j]);
  }

#pragma unroll
  for (int i = 0; i < 4; i++)
#pragma unroll
    for (int j = 0; j < 4; j++)
#pragma unroll
      for (int r = 0; r < 4; r++) {
        int row = m0 + wm + i * 16 + quad * 4 + r;
        int col = n0 + wn + j * 16 + l15;
        float v = acc[i][j][r];
        if (MODE == 0) {
          outF[(size_t)row * N + col] = v;
        } else if (MODE == 1) {
          outB[(size_t)row * N + col] = (bf16_t)v;
        } else {
          v += (float)addend[(size_t)row * addLd + addCol + col];
          int s = row & (S_LEN - 1), b = row >> 11;
          int h = col >> 7, d = col & (HD - 1);
          outB[(((size_t)(b * NHEAD + h) * S_LEN) + s) * HD + d] = (bf16_t)v;
        }
      }
}

// ---------------- blend + rmsnorm + kth-threshold + relu ----------------
__global__ __launch_bounds__(256)
void k_tsproc(const float* __restrict__ ts, const float* __restrict__ lte,
              const float* __restrict__ wn, bf16_t* __restrict__ tsf)
{
  __shared__ float sv[TSD];
  __shared__ float red[4];
  int row = blockIdx.x;
  int t = threadIdx.x;
  const float* tr = ts  + (size_t)row * TSD;
  const float* lr = lte + (size_t)row * TSD;
  float v0 = 0.5f * tr[t] + 0.5f * lr[t];
  float v1 = 0.5f * tr[t + 256] + 0.5f * lr[t + 256];
  float ss = v0 * v0 + v1 * v1;
#pragma unroll
  for (int o = 32; o > 0; o >>= 1) ss += __shfl_down(ss, o);
  int lane = t & 63, wv = t >> 6;
  if (lane == 0) red[wv] = ss;
  __syncthreads();
  float tot = red[0] + red[1] + red[2] + red[3];
  float scl = rsqrtf(tot * (1.0f / TSD) + 1e-6f);
  float n0 = v0 * scl * wn[t];
  float n1 = v1 * scl * wn[t + 256];
  sv[t] = n0; sv[t + 256] = n1;
  __syncthreads();
  for (int k = 2; k <= TSD; k <<= 1) {
    for (int j = k >> 1; j > 0; j >>= 1) {
#pragma unroll
      for (int u = 0; u < 2; u++) {
        int idx = t + u * 256;
        int ixj = idx ^ j;
        if (ixj > idx) {
          float a = sv[idx], b = sv[ixj];
          bool up = ((idx & k) == 0);
          if ((a > b) == up) { sv[idx] = b; sv[ixj] = a; }
        }
      }
      __syncthreads();
    }
  }
  float kth = sv[KIDX];
  tsf[(size_t)row * TSD + t]       = (bf16_t)fmaxf(n0 - kth, 0.0f);
  tsf[(size_t)row * TSD + t + 256] = (bf16_t)fmaxf(n1 - kth, 0.0f);
}

// ---------------- RoPE tables: tab[s][d] = cos/sin(s * 10000^(-2d/128)) ----------------
__global__ void k_ropetab(float* __restrict__ tabC, float* __restrict__ tabS) {
  int gid = blockIdx.x * 256 + threadIdx.x;   // 2048*64
  int d = gid & 63, s = gid >> 6;
  float inv = powf(10000.0f, (float)(-2 * d) * (1.0f / 128.0f));
  float sn, c;
  sincosf((float)s * inv, &sn, &c);
  tabC[gid] = c; tabS[gid] = sn;
}

// ---------------- RoPE in place on [B*NH, S, HD] bf16 ----------------
__global__ void k_rope(bf16_t* __restrict__ x, const float* __restrict__ tabC,
                       const float* __restrict__ tabS) {
  int gid = blockIdx.x * 256 + threadIdx.x;
  int d = gid & 63;
  int rowi = gid >> 6;
  int s = rowi & (S_LEN - 1);
  bf16_t* p = x + (size_t)rowi * HD;
  float c  = tabC[s * 64 + d];
  float sn = tabS[s * 64 + d];
  float x0 = (float)p[d], x1 = (float)p[d + 64];
  p[d]      = (bf16_t)(x0 * c - x1 * sn);
  p[d + 64] = (bf16_t)(x1 * c + x0 * sn);
}

// ---------------- flash attention v5 (causal) ----------------
// S^T formulation: S^T = mfma(K-frag, Q-frag) -> q-rows on l15, keys on
// (quad,reg). Softmax: in-lane 16-reduce + 2 cross-quad shuffles; scalar
// m/l/alpha per lane. P enters PV as B-operand built by ds_bpermute (no P
// LDS buffer, no bank conflicts). O^T = mfma(V^T-frag, P-frag).
// Double-buffered K/V LDS (2x32 KB), ONE barrier per step; register
// prefetch of next tile. 8 waves x 16 q-rows, Q-tile 128, XCD-aware bids.
__global__ __launch_bounds__(512, 4)
void k_attn(const bf16_t* __restrict__ qb, const bf16_t* __restrict__ kb,
            const bf16_t* __restrict__ vtb, bf16_t* __restrict__ attnB)
{
  __shared__ __align__(16) bf16_t Kt[2][64 * 128];   // [key][d], swizzled granules
  __shared__ __align__(16) bf16_t Vt[2][128 * 64];   // [d][key], swizzled granules

  const int bid = blockIdx.x;
  const int bh  = (bid & 7) + 8 * (bid >> 7);     // same head -> same XCD (bid%8)
  static const int qmap[16] = {15,0,14,1,13,2,12,3,11,4,10,5,9,6,8,7};
  const int q0 = qmap[((bid >> 3) + (bid >> 8)) & 15] * 128;

  const int tid = threadIdx.x;
  const int lane = tid & 63, w = tid >> 6;        // 8 waves
  const int quad = lane >> 4, l15 = lane & 15;

  const bf16_t* Q  = qb  + (size_t)bh * S_LEN * HD;
  const bf16_t* Kg = kb  + (size_t)bh * S_LEN * HD;
  const bf16_t* Vg = vtb + (size_t)bh * HD * S_LEN;   // [d][s]

  // Q B-fragments: wave w owns q-rows q0 + w*16 .. +15 (q = l15)
  bf16x8 qf[4];
  {
    const bf16_t* qrow = Q + (size_t)(q0 + w * 16 + l15) * HD;
#pragma unroll
    for (int c = 0; c < 4; c++)
      qf[c] = *(const bf16x8a*)(qrow + c * 32 + quad * 8);
  }

  // fragment offsets within one buffer (swizzle folded in)
  int kfo[4];
#pragma unroll
  for (int c = 0; c < 4; c++)
    kfo[c] = l15 * 128 + (((c * 4 + quad) ^ (l15 & 7)) * 8);
  int vfo[2];
#pragma unroll
  for (int kc = 0; kc < 2; kc++)
    vfo[kc] = l15 * 64 + (((kc * 4 + quad) ^ (l15 & 7)) * 8);

  // staging thread constants (512 threads, 2 granules each for K and V)
  const int kR   = tid >> 4;
  const int kCg  = tid & 15;
  const size_t kG = (size_t)kR * HD + kCg * 8;
  const int kL   = kR * 128 + ((kCg ^ (kR & 7)) * 8);
  const int vD0  = tid >> 3;
  const int vKg  = tid & 7;
  const size_t vG = (size_t)vD0 * S_LEN + vKg * 8;
  const int vL   = vD0 * 64 + ((vKg ^ (vD0 & 7)) * 8);

  // bpermute source-lane byte addresses for P B-frag build
  const int addrA = 4 * (l15 + 32 * (quad & 1));   // j=0..3 source lane
  const int addrB = addrA + 64;                    // j=4..7 source lane
  const bool selHi = (quad >> 1) != 0;             // quads 2,3 use pk[2kc+1]

  f32x4 o[8];
#pragma unroll
  for (int t8 = 0; t8 < 8; t8++) { f32x4 z = {0.f,0.f,0.f,0.f}; o[t8] = z; }
  float m_i = -1e30f, l_i = 0.0f;

  const float scale = 0.08838834764831845f;   // 1/sqrt(128)
  const int kEnd = q0 + 64;
  const int qrow_i = q0 + w * 16 + l15;       // this lane's q-row

  // ---- prologue: tile0 -> regs -> buf0; prefetch tile1 -> regs ----
  bf16x8 kr0, kr1, vr0, vr1;
  kr0 = *(const bf16x8a*)(Kg + kG);
  kr1 = *(const bf16x8a*)(Kg + kG + (size_t)32 * HD);
  vr0 = *(const bf16x8a*)(Vg + vG);
  vr1 = *(const bf16x8a*)(Vg + vG + (size_t)64 * S_LEN);
  *(bf16x8a*)(&Kt[0][0] + kL)        = kr0;
  *(bf16x8a*)(&Kt[0][0] + kL + 4096) = kr1;
  *(bf16x8a*)(&Vt[0][0] + vL)        = vr0;
  *(bf16x8a*)(&Vt[0][0] + vL + 4096) = vr1;
  {
    const int t1 = (64 <= kEnd) ? 64 : 0;
    kr0 = *(const bf16x8a*)(Kg + (size_t)t1 * HD + kG);
    kr1 = *(const bf16x8a*)(Kg + (size_t)t1 * HD + kG + (size_t)32 * HD);
    vr0 = *(const bf16x8a*)(Vg + vG + t1);
    vr1 = *(const bf16x8a*)(Vg + vG + t1 + (size_t)64 * S_LEN);
  }
  __syncthreads();

  int p = 0;
  for (int k0 = 0; k0 <= kEnd; k0 += 64) {
    const bf16_t* Kb = &Kt[p][0];
    const bf16_t* Vb = &Vt[p][0];

    // S^T = K Q^T : st[nt][r] = S[key = k0+nt*16+quad*4+r][q = qrow_i]
    f32x4 st_[4];
#pragma unroll
    for (int nt = 0; nt < 4; nt++) { f32x4 z = {0.f,0.f,0.f,0.f}; st_[nt] = z; }
#pragma unroll
    for (int nt = 0; nt < 4; nt++)
#pragma unroll
      for (int c = 0; c < 4; c++) {
        bf16x8 kf = *(const bf16x8a*)(Kb + kfo[c] + nt * 2048);
        st_[nt] = mfma_bf16(kf, qf[c], st_[nt]);
      }

    // stage next tile (already in regs) into other buffer; prefetch tile+2
    if (k0 + 64 <= kEnd) {
      bf16_t* Kw = &Kt[p ^ 1][0];
      bf16_t* Vw = &Vt[p ^ 1][0];
      *(bf16x8a*)(Kw + kL)        = kr0;
      *(bf16x8a*)(Kw + kL + 4096) = kr1;
      *(bf16x8a*)(Vw + vL)        = vr0;
      *(bf16x8a*)(Vw + vL + 4096) = vr1;
      const int t2 = (k0 + 128 <= kEnd) ? (k0 + 128) : kEnd;
      kr0 = *(const bf16x8a*)(Kg + (size_t)t2 * HD + kG);
      kr1 = *(const bf16x8a*)(Kg + (size_t)t2 * HD + kG + (size_t)32 * HD);
      vr0 = *(const bf16x8a*)(Vg + vG + t2);
      vr1 = *(const bf16x8a*)(Vg + vG + t2 + (size_t)64 * S_LEN);
    }

    // scale + causal mask (diagonal region only; wave-uniform branch)
    if (k0 + 63 > q0 + w * 16) {
#pragma unroll
      for (int nt = 0; nt < 4; nt++)
#pragma unroll
        for (int r = 0; r < 4; r++) {
          int key = k0 + nt * 16 + quad * 4 + r;
          float v = st_[nt][r] * scale;
          st_[nt][r] = (key > qrow_i) ? -1e9f : v;
        }
    } else {
#pragma unroll
      for (int nt = 0; nt < 4; nt++)
#pragma unroll
        for (int r = 0; r < 4; r++)
          st_[nt][r] *= scale;
    }

    // online softmax: in-lane 16-value reduce + 2 cross-quad shuffles
    float mx = st_[0][0];
#pragma unroll
    for (int nt = 0; nt < 4; nt++)
#pragma unroll
      for (int r = 0; r < 4; r++) mx = fmaxf(mx, st_[nt][r]);
    mx = fmaxf(mx, __shfl_xor(mx, 16));
    mx = fmaxf(mx, __shfl_xor(mx, 32));
    float mnew = fmaxf(m_i, mx);
    float alpha = __expf(m_i - mnew);
    m_i = mnew;
    float rs = 0.0f;
#pragma unroll
    for (int nt = 0; nt < 4; nt++)
#pragma unroll
      for (int r = 0; r < 4; r++) {
        float pv = __expf(st_[nt][r] - mnew);
        st_[nt][r] = pv;
        rs += pv;
      }
    rs += __shfl_xor(rs, 16);
    rs += __shfl_xor(rs, 32);
    l_i = l_i * alpha + rs;

    // pack P to bf16 pairs (per nt: regs 0,1 and 2,3)
    uint32_t pk[4][2];
#pragma unroll
    for (int nt = 0; nt < 4; nt++) {
      pk[nt][0] = pk2(st_[nt][0], st_[nt][1]);
      pk[nt][1] = pk2(st_[nt][2], st_[nt][3]);
    }

    // rescale O
#pragma unroll
    for (int t8 = 0; t8 < 8; t8++)
#pragma unroll
      for (int r = 0; r < 4; r++)
        o[t8][r] *= alpha;

    // O^T += V^T * P : build P B-frag via bpermute, then MFMA over d-tiles
#pragma unroll
    for (int kc = 0; kc < 2; kc++) {
      uint32_t a0 = __builtin_amdgcn_ds_bpermute(addrA, (int)pk[2*kc][0]);
      uint32_t a1 = __builtin_amdgcn_ds_bpermute(addrA, (int)pk[2*kc][1]);
      uint32_t a2 = __builtin_amdgcn_ds_bpermute(addrB, (int)pk[2*kc][0]);
      uint32_t a3 = __builtin_amdgcn_ds_bpermute(addrB, (int)pk[2*kc][1]);
      uint32_t b0 = __builtin_amdgcn_ds_bpermute(addrA, (int)pk[2*kc+1][0]);
      uint32_t b1 = __builtin_amdgcn_ds_bpermute(addrA, (int)pk[2*kc+1][1]);
      uint32_t b2 = __builtin_amdgcn_ds_bpermute(addrB, (int)pk[2*kc+1][0]);
      uint32_t b3 = __builtin_amdgcn_ds_bpermute(addrB, (int)pk[2*kc+1][1]);
      union { bf16x8 v; uint32_t d[4]; } pf;
      pf.d[0] = selHi ? b0 : a0;
      pf.d[1] = selHi ? b1 : a1;
      pf.d[2] = selHi ? b2 : a2;
      pf.d[3] = selHi ? b3 : a3;
#pragma unroll
      for (int t8 = 0; t8 < 8; t8++) {
        bf16x8 vf = *(const bf16x8a*)(Vb + vfo[kc] + t8 * 1024);
        o[t8] = mfma_bf16(vf, pf.v, o[t8]);
      }
    }

    __syncthreads();
    p ^= 1;
  }

  // epilogue: O^T[d][q]: lane q = l15; d = t8*16 + quad*4 + r
  const int b = bh >> 4, h = bh & 15;
  const float rl = 1.0f / l_i;
  uint32_t* outp = (uint32_t*)(attnB + (size_t)(b * S_LEN + qrow_i) * HDIM + h * HD);
#pragma unroll
  for (int t8 = 0; t8 < 8; t8++)
#pragma unroll
    for (int pr = 0; pr < 2; pr++) {
      uint32_t v = pk2(o[t8][2*pr] * rl, o[t8][2*pr+1] * rl);
      outp[t8 * 8 + quad * 2 + pr] = v;
    }
}

// ---------------- launcher ----------------
extern "C" void kernel_launch(void* const* d_in, const int* in_sizes, int n_in,
                              void* d_out, int out_size, void* d_ws, size_t ws_size,
                              hipStream_t stream) {
  const float* hs    = (const float*)d_in[0];
  const float* lte   = (const float*)d_in[1];
  const float* Wq    = (const float*)d_in[2];
  const float* Wk    = (const float*)d_in[3];
  const float* Wv    = (const float*)d_in[4];
  const float* Wo    = (const float*)d_in[5];
  const float* Wts   = (const float*)d_in[6];
  const float* tsw   = (const float*)d_in[7];
  const float* Worig = (const float*)d_in[8];
  float* out = (float*)d_out;

  char* p = (char*)d_ws;
  bf16_t* hsB   = (bf16_t*)(p);                    // 16 MB [4096][2048]
  bf16_t* wT    = (bf16_t*)(p + 16777216);         //  8 MB reused per GEMM
  float*  tsB   = (float*)(p + 25165824);          //  8 MB [4096][512]; rope tabs after tsproc
  bf16_t* tsf   = (bf16_t*)(p + 33554432);         //  4 MB [4096][512]
  bf16_t* qkadd = (bf16_t*)(p + 37748736);         // 32 MB [4096][4096] (dead after QKV)
  bf16_t* attnB = qkadd;                           // 16 MB alias (lower half)
  bf16_t* vtb   = (bf16_t*)(p + 54525952);         // 16 MB alias (upper half) [bh][d][s]
  bf16_t* qbuf  = (bf16_t*)(p + 71303168);         // 16 MB [32][2048][128]
  bf16_t* kbuf  = (bf16_t*)(p + 88080384);         // 16 MB
  bf16_t* vbuf  = (bf16_t*)(p + 104857600);        // 16 MB -> total 121,634,816
  float*  tabC  = tsB;                             // 512 KB (tsB dead after k_tsproc)
  float*  tabS  = tsB + 131072;                    // 512 KB

  k_cvt<<<8192, 256, 0, stream>>>(hs, hsB, BROWS * HDIM);
  k_transpose<<<dim3(16, 64), dim3(32, 8), 0, stream>>>(Wts, wT, 2048, 512, 512);
  k_gemm<0><<<dim3(4, 32), 256, 0, stream>>>(hsB, wT, tsB, nullptr, nullptr,
                                             4096, 512, 2048, 0, 0);
  k_tsproc<<<4096, 256, 0, stream>>>(tsB, lte, tsw, tsf);
  k_ropetab<<<512, 256, 0, stream>>>(tabC, tabS);
  k_transpose<<<dim3(128, 16), dim3(32, 8), 0, stream>>>(Worig, wT, 512, 4096, 6144);
  k_gemm<1><<<dim3(32, 32), 256, 0, stream>>>(tsf, wT, nullptr, qkadd, nullptr,
                                              4096, 4096, 512, 0, 0);
  k_transpose<<<dim3(64, 64), dim3(32, 8), 0, stream>>>(Wq, wT, 2048, 2048, 2048);
  k_gemm<2><<<dim3(16, 32), 256, 0, stream>>>(hsB, wT, nullptr, qbuf, qkadd,
                                              4096, 2048, 2048, 4096, 0);
  k_transpose<<<dim3(64, 64), dim3(32, 8), 0, stream>>>(Wk, wT, 2048, 2048, 2048);
  k_gemm<2><<<dim3(16, 32), 256, 0, stream>>>(hsB, wT, nullptr, kbuf, qkadd,
                                              4096, 2048, 2048, 4096, 2048);
  k_transpose<<<dim3(64, 64), dim3(32, 8), 0, stream>>>(Wv, wT, 2048, 2048, 2048);
  k_gemm<2><<<dim3(16, 32), 256, 0, stream>>>(hsB, wT, nullptr, vbuf, qkadd,
                                              4096, 2048, 2048, 4096, 2048);
  k_rope<<<16384, 256, 0, stream>>>(qbuf, tabC, tabS);
  k_rope<<<16384, 256, 0, stream>>>(kbuf, tabC, tabS);
  k_vtrans<<<dim3(32, 2, 32), 256, 0, stream>>>(vbuf, vtb);
  k_transpose<<<dim3(64, 64), dim3(32, 8), 0, stream>>>(Wo, wT, 2048, 2048, 2048);
  k_attn<<<512, 512, 0, stream>>>(qbuf, kbuf, vtb, attnB);
  k_gemm<0><<<dim3(16, 32), 256, 0, stream>>>(attnB, wT, out, nullptr, nullptr,
                                              4096, 2048, 2048, 0, 0);
}